// Round 2
// baseline (2500.344 us; speedup 1.0000x reference)
//
#include <hip/hip_runtime.h>
#include <cstdint>
#include <cstddef>

#define NNODES 50000
#define NEDGES 400000
#define NTOT   450000     // edges + self loops
#define INC    256
#define D1     512        // HEADS*HID
#define OUTC   256
#define NEG    0.2f

// ---------------- GEMM: C[M,Nc] = op(A)[M,K] @ B[K,Nc] ----------------
// BM=BN=128, BK=16, 256 threads, 8x8 microtile. RELU => a = relu(a + bias[k])
template<bool RELU>
__global__ __launch_bounds__(256) void gemm128(const float* __restrict__ A,
    const float* __restrict__ B, const float* __restrict__ bias,
    float* __restrict__ C, int M, int K, int Nc) {
  __shared__ float As[16][132];
  __shared__ float Bs[16][132];
  const int tid = threadIdx.x;
  const int tx = tid & 15, ty = tid >> 4;
  const int bm = blockIdx.y * 128, bn = blockIdx.x * 128;
  float acc[8][8];
#pragma unroll
  for (int i = 0; i < 8; ++i)
#pragma unroll
    for (int j = 0; j < 8; ++j) acc[i][j] = 0.f;

  for (int k0 = 0; k0 < K; k0 += 16) {
#pragma unroll
    for (int l = 0; l < 8; ++l) {
      int idx = tid + 256 * l;          // 0..2047 over 128x16 A tile
      int r = idx >> 4, c = idx & 15;
      int row = bm + r;
      float v = 0.f;
      if (row < M) {
        v = A[(size_t)row * K + (k0 + c)];
        if (RELU) { v += bias[k0 + c]; v = v > 0.f ? v : 0.f; }
      }
      As[c][r] = v;
    }
#pragma unroll
    for (int l = 0; l < 8; ++l) {
      int idx = tid + 256 * l;          // 16x128 B tile
      int r = idx >> 7, c = idx & 127;
      Bs[r][c] = B[(size_t)(k0 + r) * Nc + (bn + c)];
    }
    __syncthreads();
#pragma unroll
    for (int kk = 0; kk < 16; ++kk) {
      float a[8], b[8];
#pragma unroll
      for (int i = 0; i < 8; ++i) a[i] = As[kk][ty * 8 + i];
#pragma unroll
      for (int j = 0; j < 8; ++j) b[j] = Bs[kk][tx * 8 + j];
#pragma unroll
      for (int i = 0; i < 8; ++i)
#pragma unroll
        for (int j = 0; j < 8; ++j) acc[i][j] = fmaf(a[i], b[j], acc[i][j]);
    }
    __syncthreads();
  }
#pragma unroll
  for (int i = 0; i < 8; ++i) {
    int row = bm + ty * 8 + i;
    if (row < M) {
#pragma unroll
      for (int j = 0; j < 8; ++j)
        C[(size_t)row * Nc + bn + tx * 8 + j] = acc[i][j];
    }
  }
}

// ------------- grid-stride zero -------------
__global__ __launch_bounds__(256) void zero_k(float* __restrict__ p, int n) {
  int stride = gridDim.x * 256;
  for (int i = blockIdx.x * 256 + threadIdx.x; i < n; i += stride) p[i] = 0.f;
}

// ------------- layer-1 scores: one wave per edge, 4 heads x 128 ch -------------
__global__ __launch_bounds__(256) void score1_k(const int* __restrict__ srcs,
    const int* __restrict__ dsts, const float* __restrict__ XL,
    const float* __restrict__ XR, const float* __restrict__ a1,
    float* __restrict__ P, float* __restrict__ denom) {
  int e = blockIdx.x * 4 + (threadIdx.x >> 6);
  if (e >= NTOT) return;
  int lane = threadIdx.x & 63;
  int s, d;
  if (e < NEDGES) { s = srcs[e]; d = dsts[e]; } else { s = d = e - NEDGES; }
  const float* xl = XL + (size_t)s * D1;
  const float* xr = XR + (size_t)d * D1;
  float acc[4];
#pragma unroll
  for (int h = 0; h < 4; ++h) {
    int c0 = h * 128 + lane;
    float g0 = xl[c0] + xr[c0];
    float g1 = xl[c0 + 64] + xr[c0 + 64];
    g0 = g0 > 0.f ? g0 : NEG * g0;
    g1 = g1 > 0.f ? g1 : NEG * g1;
    acc[h] = g0 * a1[h * 128 + lane] + g1 * a1[h * 128 + lane + 64];
  }
#pragma unroll
  for (int off = 32; off > 0; off >>= 1) {
#pragma unroll
    for (int h = 0; h < 4; ++h) acc[h] += __shfl_xor(acc[h], off);
  }
  if (lane == 0) {
#pragma unroll
    for (int h = 0; h < 4; ++h) {
      float p = __expf(acc[h]);
      P[(size_t)e * 4 + h] = p;
      atomicAdd(&denom[(size_t)d * 4 + h], p);
    }
  }
}

// ------------- layer-1 aggregation: atomic scatter alpha * xl[src] -------------
__global__ __launch_bounds__(256) void agg1_k(const int* __restrict__ srcs,
    const int* __restrict__ dsts, const float* __restrict__ XL,
    const float* __restrict__ P, const float* __restrict__ denom,
    float* __restrict__ H) {
  int e = blockIdx.x * 4 + (threadIdx.x >> 6);
  if (e >= NTOT) return;
  int lane = threadIdx.x & 63;
  int s, d;
  if (e < NEDGES) { s = srcs[e]; d = dsts[e]; } else { s = d = e - NEDGES; }
  float alpha[4];
#pragma unroll
  for (int h = 0; h < 4; ++h)
    alpha[h] = P[(size_t)e * 4 + h] / denom[(size_t)d * 4 + h];
  const float* xl = XL + (size_t)s * D1;
  float* o = H + (size_t)d * D1;
#pragma unroll
  for (int t = 0; t < 8; ++t) {
    int c = t * 64 + lane;
    atomicAdd(&o[c], alpha[t >> 1] * xl[c]);
  }
}

// ------------- layer-2 scores: 1 head x 256 ch -------------
__global__ __launch_bounds__(256) void score2_k(const int* __restrict__ srcs,
    const int* __restrict__ dsts, const float* __restrict__ XL,
    const float* __restrict__ XR, const float* __restrict__ a2,
    float* __restrict__ P, float* __restrict__ denom) {
  int e = blockIdx.x * 4 + (threadIdx.x >> 6);
  if (e >= NTOT) return;
  int lane = threadIdx.x & 63;
  int s, d;
  if (e < NEDGES) { s = srcs[e]; d = dsts[e]; } else { s = d = e - NEDGES; }
  const float* xl = XL + (size_t)s * OUTC;
  const float* xr = XR + (size_t)d * OUTC;
  float acc = 0.f;
#pragma unroll
  for (int t = 0; t < 4; ++t) {
    int c = t * 64 + lane;
    float g = xl[c] + xr[c];
    g = g > 0.f ? g : NEG * g;
    acc += g * a2[c];
  }
#pragma unroll
  for (int off = 32; off > 0; off >>= 1) acc += __shfl_xor(acc, off);
  if (lane == 0) {
    float p = __expf(acc);
    P[e] = p;
    atomicAdd(&denom[d], p);
  }
}

// ------------- layer-2 aggregation into d_out -------------
__global__ __launch_bounds__(256) void agg2_k(const int* __restrict__ srcs,
    const int* __restrict__ dsts, const float* __restrict__ XL,
    const float* __restrict__ P, const float* __restrict__ denom,
    float* __restrict__ out) {
  int e = blockIdx.x * 4 + (threadIdx.x >> 6);
  if (e >= NTOT) return;
  int lane = threadIdx.x & 63;
  int s, d;
  if (e < NEDGES) { s = srcs[e]; d = dsts[e]; } else { s = d = e - NEDGES; }
  float alpha = P[e] / denom[d];
  const float* xl = XL + (size_t)s * OUTC;
  float* o = out + (size_t)d * OUTC;
#pragma unroll
  for (int t = 0; t < 4; ++t) {
    int c = t * 64 + lane;
    atomicAdd(&o[c], alpha * xl[c]);
  }
}

// ------------- init output to broadcast bias b2 -------------
__global__ __launch_bounds__(256) void init_out_k(float* __restrict__ out,
                                                  const float* __restrict__ b2) {
  int gid = blockIdx.x * 256 + threadIdx.x;
  out[gid] = b2[gid & 255];
}

extern "C" void kernel_launch(void* const* d_in, const int* in_sizes, int n_in,
                              void* d_out, int out_size, void* d_ws, size_t ws_size,
                              hipStream_t stream) {
  const float* x   = (const float*)d_in[0];
  const int*   ei  = (const int*)d_in[1];
  const float* W1l = (const float*)d_in[2];
  const float* W1r = (const float*)d_in[3];
  const float* a1  = (const float*)d_in[4];
  const float* b1  = (const float*)d_in[5];
  const float* W2l = (const float*)d_in[6];
  const float* W2r = (const float*)d_in[7];
  const float* a2  = (const float*)d_in[8];
  const float* b2  = (const float*)d_in[9];
  float* out = (float*)d_out;
  char* ws = (char*)d_ws;

  // ---- workspace layout: 214,800,000 bytes total ----
  // BufA [0 .. 102.4MB):        XL1, later XL2 (first 51.2MB) + XR2 (next 51.2MB)
  // BufB [102.4 .. 204.8MB):    XR1, later H (aliased; XR1 dead after score1)
  float* XL1  = (float*)(ws + 0);
  float* XR1  = (float*)(ws + 102400000);
  float* H    = XR1;
  float* XL2  = (float*)(ws + 0);
  float* XR2  = (float*)(ws + 51200000);
  float* P1   = (float*)(ws + 204800000);   // 7,200,000 B
  float* den1 = (float*)(ws + 212000000);   //   800,000 B
  float* P2   = (float*)(ws + 212800000);   // 1,800,000 B
  float* den2 = (float*)(ws + 214600000);   //   200,000 B

  const int* srcs = ei;
  const int* dsts = ei + NEDGES;

  dim3 blk(256);
  int eblocks = (NTOT + 3) / 4;

  // ---- layer 1 linear transforms ----
  dim3 g1(D1 / 128, (NNODES + 127) / 128);
  gemm128<false><<<g1, blk, 0, stream>>>(x, W1l, nullptr, XL1, NNODES, INC, D1);
  gemm128<false><<<g1, blk, 0, stream>>>(x, W1r, nullptr, XR1, NNODES, INC, D1);

  // ---- layer 1 attention ----
  zero_k<<<512, blk, 0, stream>>>(den1, NNODES * 4);
  score1_k<<<eblocks, blk, 0, stream>>>(srcs, dsts, XL1, XR1, a1, P1, den1);
  zero_k<<<2048, blk, 0, stream>>>(H, NNODES * D1);   // after score1: H aliases XR1
  agg1_k<<<eblocks, blk, 0, stream>>>(srcs, dsts, XL1, P1, den1, H);

  // ---- layer 2 linear transforms (relu(H + b1) fused into A-load) ----
  dim3 g2(OUTC / 128, (NNODES + 127) / 128);
  gemm128<true><<<g2, blk, 0, stream>>>(H, W2l, b1, XL2, NNODES, D1, OUTC);
  gemm128<true><<<g2, blk, 0, stream>>>(H, W2r, b1, XR2, NNODES, D1, OUTC);

  // ---- layer 2 attention ----
  init_out_k<<<(NNODES * OUTC) / 256, blk, 0, stream>>>(out, b2);
  zero_k<<<512, blk, 0, stream>>>(den2, NNODES);
  score2_k<<<eblocks, blk, 0, stream>>>(srcs, dsts, XL2, XR2, a2, P2, den2);
  agg2_k<<<eblocks, blk, 0, stream>>>(srcs, dsts, XL2, P2, den2, out);
}

// Round 4
// 1329.992 us; speedup vs baseline: 1.8800x; 1.8800x over previous
//
#include <hip/hip_runtime.h>
#include <cstdint>
#include <cstddef>

#define NNODES 50000
#define NEDGES 400000
#define INC    256
#define D1     512        // HEADS*HID
#define OUTC   256
#define NEG    0.2f
#define NB     196        // ceil(NNODES/256)

// ---------------- GEMM: C[M,Nc] = op(A)[M,K] @ B[K,Nc] ----------------
template<bool RELU>
__global__ __launch_bounds__(256) void gemm128(const float* __restrict__ A,
    const float* __restrict__ B, const float* __restrict__ bias,
    float* __restrict__ C, int M, int K, int Nc) {
  __shared__ float As[16][132];
  __shared__ float Bs[16][132];
  const int tid = threadIdx.x;
  const int tx = tid & 15, ty = tid >> 4;
  const int bm = blockIdx.y * 128, bn = blockIdx.x * 128;
  float acc[8][8];
#pragma unroll
  for (int i = 0; i < 8; ++i)
#pragma unroll
    for (int j = 0; j < 8; ++j) acc[i][j] = 0.f;

  for (int k0 = 0; k0 < K; k0 += 16) {
#pragma unroll
    for (int l = 0; l < 8; ++l) {
      int idx = tid + 256 * l;
      int r = idx >> 4, c = idx & 15;
      int row = bm + r;
      float v = 0.f;
      if (row < M) {
        v = A[(size_t)row * K + (k0 + c)];
        if (RELU) { v += bias[k0 + c]; v = v > 0.f ? v : 0.f; }
      }
      As[c][r] = v;
    }
#pragma unroll
    for (int l = 0; l < 8; ++l) {
      int idx = tid + 256 * l;
      int r = idx >> 7, c = idx & 127;
      Bs[r][c] = B[(size_t)(k0 + r) * Nc + (bn + c)];
    }
    __syncthreads();
#pragma unroll
    for (int kk = 0; kk < 16; ++kk) {
      float a[8], b[8];
#pragma unroll
      for (int i = 0; i < 8; ++i) a[i] = As[kk][ty * 8 + i];
#pragma unroll
      for (int j = 0; j < 8; ++j) b[j] = Bs[kk][tx * 8 + j];
#pragma unroll
      for (int i = 0; i < 8; ++i)
#pragma unroll
        for (int j = 0; j < 8; ++j) acc[i][j] = fmaf(a[i], b[j], acc[i][j]);
    }
    __syncthreads();
  }
#pragma unroll
  for (int i = 0; i < 8; ++i) {
    int row = bm + ty * 8 + i;
    if (row < M) {
#pragma unroll
      for (int j = 0; j < 8; ++j)
        C[(size_t)row * Nc + bn + tx * 8 + j] = acc[i][j];
    }
  }
}

// ---------------- CSR build ----------------
__global__ __launch_bounds__(256) void zero_i_k(int* __restrict__ p, int n) {
  int stride = gridDim.x * 256;
  for (int i = blockIdx.x * 256 + threadIdx.x; i < n; i += stride) p[i] = 0;
}

__global__ __launch_bounds__(256) void hist_k(const int* __restrict__ dsts,
                                              int* __restrict__ deg) {
  int e = blockIdx.x * 256 + threadIdx.x;
  if (e < NEDGES) atomicAdd(&deg[dsts[e]], 1);
}

__global__ __launch_bounds__(256) void bsum_k(const int* __restrict__ deg,
                                              int* __restrict__ bsum) {
  __shared__ int red[256];
  int t = threadIdx.x, i = blockIdx.x * 256 + t;
  red[t] = (i < NNODES) ? deg[i] : 0;
  __syncthreads();
#pragma unroll
  for (int off = 128; off > 0; off >>= 1) {
    if (t < off) red[t] += red[t + off];
    __syncthreads();
  }
  if (t == 0) bsum[blockIdx.x] = red[0];
}

__global__ __launch_bounds__(64) void bscan_k(const int* __restrict__ bsum,
                                              int* __restrict__ bscan) {
  if (threadIdx.x == 0) {
    int run = 0;
    for (int j = 0; j < NB; ++j) { bscan[j] = run; run += bsum[j]; }
  }
}

__global__ __launch_bounds__(256) void rowptr_k(const int* __restrict__ deg,
    const int* __restrict__ bscan, int* __restrict__ rowptr,
    int* __restrict__ cursor) {
  __shared__ int s[256];
  int t = threadIdx.x, b = blockIdx.x, i = b * 256 + t;
  int v = (i < NNODES) ? deg[i] : 0;
  s[t] = v;
  __syncthreads();
#pragma unroll
  for (int off = 1; off < 256; off <<= 1) {
    int y = (t >= off) ? s[t - off] : 0;
    __syncthreads();
    s[t] += y;
    __syncthreads();
  }
  if (i < NNODES) {
    int ex = bscan[b] + s[t] - v;   // exclusive prefix
    rowptr[i] = ex;
    cursor[i] = ex;
  }
  if (b == 0 && t == 0) rowptr[NNODES] = NEDGES;
}

__global__ __launch_bounds__(256) void scatter_k(const int* __restrict__ srcs,
    const int* __restrict__ dsts, int* __restrict__ cursor,
    int* __restrict__ col) {
  int e = blockIdx.x * 256 + threadIdx.x;
  if (e < NEDGES) {
    int pos = atomicAdd(&cursor[dsts[e]], 1);
    col[pos] = srcs[e];
  }
}

// ---------------- fused layer-1 attention: one wave per dst node ----------------
// lane channel c = t*64+lane (t=0..7); head h = t>>1
__global__ __launch_bounds__(256) void fused1_k(const int* __restrict__ rowptr,
    const int* __restrict__ col, const float* __restrict__ XL,
    const float* __restrict__ XR, const float* __restrict__ a1,
    float* __restrict__ H) {
  int d = blockIdx.x * 4 + (threadIdx.x >> 6);
  if (d >= NNODES) return;
  int lane = threadIdx.x & 63;
  float av[8], xr[8], acc[8];
#pragma unroll
  for (int t = 0; t < 8; ++t) {
    av[t] = a1[t * 64 + lane];
    xr[t] = XR[(size_t)d * D1 + t * 64 + lane];
    acc[t] = 0.f;
  }
  float den[4] = {0.f, 0.f, 0.f, 0.f};
  int beg = rowptr[d], end = rowptr[d + 1];
  for (int i = beg - 1; i < end; ++i) {   // i==beg-1 -> self loop
    int s = (i < beg) ? d : col[i];
    const float* xlp = XL + (size_t)s * D1;
    float xl[8];
#pragma unroll
    for (int t = 0; t < 8; ++t) xl[t] = xlp[t * 64 + lane];
    float part[4];
#pragma unroll
    for (int h = 0; h < 4; ++h) {
      float g0 = xl[2 * h] + xr[2 * h];
      float g1 = xl[2 * h + 1] + xr[2 * h + 1];
      g0 = g0 > 0.f ? g0 : NEG * g0;
      g1 = g1 > 0.f ? g1 : NEG * g1;
      part[h] = g0 * av[2 * h] + g1 * av[2 * h + 1];
    }
#pragma unroll
    for (int off = 32; off > 0; off >>= 1) {
#pragma unroll
      for (int h = 0; h < 4; ++h) part[h] += __shfl_xor(part[h], off);
    }
    float p[4];
#pragma unroll
    for (int h = 0; h < 4; ++h) { p[h] = __expf(part[h]); den[h] += p[h]; }
#pragma unroll
    for (int t = 0; t < 8; ++t) acc[t] = fmaf(p[t >> 1], xl[t], acc[t]);
  }
#pragma unroll
  for (int t = 0; t < 8; ++t)
    H[(size_t)d * D1 + t * 64 + lane] = acc[t] / den[t >> 1];
}

// ---------------- fused layer-2 attention: one wave per dst node ----------------
// lane channel c = t*64+lane (t=0..3); 1 head; writes out + b2 directly
__global__ __launch_bounds__(256) void fused2_k(const int* __restrict__ rowptr,
    const int* __restrict__ col, const float* __restrict__ XL,
    const float* __restrict__ XR, const float* __restrict__ a2,
    const float* __restrict__ b2, float* __restrict__ out) {
  int d = blockIdx.x * 4 + (threadIdx.x >> 6);
  if (d >= NNODES) return;
  int lane = threadIdx.x & 63;
  float av[4], xr[4], acc[4];
#pragma unroll
  for (int t = 0; t < 4; ++t) {
    av[t] = a2[t * 64 + lane];
    xr[t] = XR[(size_t)d * OUTC + t * 64 + lane];
    acc[t] = 0.f;
  }
  float den = 0.f;
  int beg = rowptr[d], end = rowptr[d + 1];
  for (int i = beg - 1; i < end; ++i) {
    int s = (i < beg) ? d : col[i];
    const float* xlp = XL + (size_t)s * OUTC;
    float xl[4];
#pragma unroll
    for (int t = 0; t < 4; ++t) xl[t] = xlp[t * 64 + lane];
    float part = 0.f;
#pragma unroll
    for (int t = 0; t < 4; ++t) {
      float g = xl[t] + xr[t];
      g = g > 0.f ? g : NEG * g;
      part = fmaf(g, av[t], part);
    }
#pragma unroll
    for (int off = 32; off > 0; off >>= 1) part += __shfl_xor(part, off);
    float p = __expf(part);
    den += p;
#pragma unroll
    for (int t = 0; t < 4; ++t) acc[t] = fmaf(p, xl[t], acc[t]);
  }
#pragma unroll
  for (int t = 0; t < 4; ++t)
    out[(size_t)d * OUTC + t * 64 + lane] = acc[t] / den + b2[t * 64 + lane];
}

extern "C" void kernel_launch(void* const* d_in, const int* in_sizes, int n_in,
                              void* d_out, int out_size, void* d_ws, size_t ws_size,
                              hipStream_t stream) {
  const float* x   = (const float*)d_in[0];
  const int*   ei  = (const int*)d_in[1];
  const float* W1l = (const float*)d_in[2];
  const float* W1r = (const float*)d_in[3];
  const float* a1  = (const float*)d_in[4];
  const float* b1  = (const float*)d_in[5];
  const float* W2l = (const float*)d_in[6];
  const float* W2r = (const float*)d_in[7];
  const float* a2  = (const float*)d_in[8];
  const float* b2  = (const float*)d_in[9];
  float* out = (float*)d_out;
  char* ws = (char*)d_ws;

  // ---- workspace layout (~207 MB) ----
  float* XL1  = (float*)(ws + 0);            // 102.4 MB
  float* XR1  = (float*)(ws + 102400000);    // 102.4 MB
  float* H    = XR1;                         // fused1: reads XR1[d] first, writes H[d] last -> safe alias
  float* XL2  = (float*)(ws + 0);            // reuse after fused1
  float* XR2  = (float*)(ws + 51200000);
  int* rowptr = (int*)(ws + 204800000);      // 50001
  int* cursor = (int*)(ws + 205004800);      // 50000
  int* col    = (int*)(ws + 205204800);      // 400000
  int* deg    = (int*)(ws + 206804800);      // 50000
  int* bsum   = (int*)(ws + 207004800);      // 196
  int* bscan  = (int*)(ws + 207005600);      // 196

  const int* srcs = ei;
  const int* dsts = ei + NEDGES;

  dim3 blk(256);
  int eblk = (NEDGES + 255) / 256;
  int nblk4 = (NNODES + 3) / 4;

  // ---- CSR build (grouped by dst) ----
  zero_i_k<<<64, blk, 0, stream>>>(deg, NNODES);
  hist_k<<<eblk, blk, 0, stream>>>(dsts, deg);
  bsum_k<<<NB, blk, 0, stream>>>(deg, bsum);
  bscan_k<<<1, 64, 0, stream>>>(bsum, bscan);
  rowptr_k<<<NB, blk, 0, stream>>>(deg, bscan, rowptr, cursor);
  scatter_k<<<eblk, blk, 0, stream>>>(srcs, dsts, cursor, col);

  // ---- layer 1 linear transforms ----
  dim3 g1(D1 / 128, (NNODES + 127) / 128);
  gemm128<false><<<g1, blk, 0, stream>>>(x, W1l, nullptr, XL1, NNODES, INC, D1);
  gemm128<false><<<g1, blk, 0, stream>>>(x, W1r, nullptr, XR1, NNODES, INC, D1);

  // ---- layer 1 fused attention (score+softmax+aggregate) ----
  fused1_k<<<nblk4, blk, 0, stream>>>(rowptr, col, XL1, XR1, a1, H);

  // ---- layer 2 linear transforms (relu(H + b1) fused into A-load) ----
  dim3 g2(OUTC / 128, (NNODES + 127) / 128);
  gemm128<true><<<g2, blk, 0, stream>>>(H, W2l, b1, XL2, NNODES, D1, OUTC);
  gemm128<true><<<g2, blk, 0, stream>>>(H, W2r, b1, XR2, NNODES, D1, OUTC);

  // ---- layer 2 fused attention -> out (+b2) ----
  fused2_k<<<nblk4, blk, 0, stream>>>(rowptr, col, XL2, XR2, a2, b2, out);
}

// Round 7
// 571.817 us; speedup vs baseline: 4.3726x; 2.3259x over previous
//
#include <hip/hip_runtime.h>
#include <cstdint>
#include <cstddef>

#define NNODES 50000
#define NEDGES 400000
#define INC    256
#define D1     512        // HEADS*HID
#define OUTC   256
#define NEG    0.2f
#define NB     196        // ceil(NNODES/256)

typedef __attribute__((ext_vector_type(8))) short short8;
typedef __attribute__((ext_vector_type(4))) float f32x4;

__device__ inline short f2bf(float f) {
  union { float f; uint32_t u; } v; v.f = f;
  uint32_t r = (v.u + 0x7fffu + ((v.u >> 16) & 1u)) >> 16;
  return (short)(r & 0xffffu);
}

// ---------------- convert x -> bf16 (8 elems/thread) ----------------
__global__ __launch_bounds__(256) void cvt_x_k(const float* __restrict__ x,
                                               short* __restrict__ xb) {
  size_t base = ((size_t)blockIdx.x * 256 + threadIdx.x) * 8;
  f32x4 a = *(const f32x4*)&x[base];
  f32x4 b = *(const f32x4*)&x[base + 4];
  short8 o;
  o[0] = f2bf(a[0]); o[1] = f2bf(a[1]); o[2] = f2bf(a[2]); o[3] = f2bf(a[3]);
  o[4] = f2bf(b[0]); o[5] = f2bf(b[1]); o[6] = f2bf(b[2]); o[7] = f2bf(b[3]);
  *(short8*)&xb[base] = o;
}

// ---------------- transpose W[K][N] f32 -> WT[N][K] bf16 ----------------
__global__ __launch_bounds__(256) void twb_k(const float* __restrict__ W,
                                             short* __restrict__ WT,
                                             int K, int N) {
  __shared__ float tile[32][33];
  int tx = threadIdx.x & 31, ty = threadIdx.x >> 5;   // ty 0..7
  int n0 = blockIdx.x * 32, k0 = blockIdx.y * 32;
#pragma unroll
  for (int i = 0; i < 4; ++i)
    tile[ty + i * 8][tx] = W[(size_t)(k0 + ty + i * 8) * N + n0 + tx];
  __syncthreads();
#pragma unroll
  for (int i = 0; i < 4; ++i) {
    int n = ty + i * 8;
    WT[(size_t)(n0 + n) * K + k0 + tx] = f2bf(tile[tx][n]);
  }
}

// ---------------- bf16 MFMA GEMM: C[M,Nc] = A[M,K] @ BT[Nc,K]^T ----------------
// 128x128 tile, BK=64, 4 waves (2x2), 4x4 16x16 frags per wave, f32 out.
#define LDT 72
__global__ __launch_bounds__(256) void gemm_bf16_k(const short* __restrict__ A,
    const short* __restrict__ BT, float* __restrict__ C, int M, int K, int Nc) {
  __shared__ short As[128 * LDT];
  __shared__ short Bs[128 * LDT];
  const int tid = threadIdx.x;
  const int lane = tid & 63, wave = tid >> 6;
  const int wr = wave >> 1, wc = wave & 1;
  const int l15 = lane & 15, l4 = lane >> 4;
  const int bm = blockIdx.y * 128, bn = blockIdx.x * 128;

  f32x4 zero4 = {0.f, 0.f, 0.f, 0.f};
  f32x4 acc[4][4];
#pragma unroll
  for (int m = 0; m < 4; ++m)
#pragma unroll
    for (int n = 0; n < 4; ++n) acc[m][n] = zero4;

  for (int k0 = 0; k0 < K; k0 += 64) {
#pragma unroll
    for (int i = 0; i < 4; ++i) {
      int q = tid + 256 * i;
      int row = q >> 3, kc = q & 7;       // 128 rows x 8 chunks of 8 bf16
      short8 va = {0, 0, 0, 0, 0, 0, 0, 0};
      int gr = bm + row;
      if (gr < M) va = *(const short8*)&A[(size_t)gr * K + k0 + kc * 8];
      *(short8*)&As[row * LDT + kc * 8] = va;
      short8 vb = *(const short8*)&BT[(size_t)(bn + row) * K + k0 + kc * 8];
      *(short8*)&Bs[row * LDT + kc * 8] = vb;
    }
    __syncthreads();
    short8 af[4][2], bf[4][2];
#pragma unroll
    for (int m = 0; m < 4; ++m)
#pragma unroll
      for (int kk = 0; kk < 2; ++kk)
        af[m][kk] = *(const short8*)&As[(wr * 64 + m * 16 + l15) * LDT + kk * 32 + l4 * 8];
#pragma unroll
    for (int n = 0; n < 4; ++n)
#pragma unroll
      for (int kk = 0; kk < 2; ++kk)
        bf[n][kk] = *(const short8*)&Bs[(wc * 64 + n * 16 + l15) * LDT + kk * 32 + l4 * 8];
#pragma unroll
    for (int kk = 0; kk < 2; ++kk)
#pragma unroll
      for (int m = 0; m < 4; ++m)
#pragma unroll
        for (int n = 0; n < 4; ++n)
          acc[m][n] = __builtin_amdgcn_mfma_f32_16x16x32_bf16(
              af[m][kk], bf[n][kk], acc[m][n], 0, 0, 0);
    __syncthreads();
  }
  // C/D layout (m89-verified): col = lane&15, row = (lane>>4)*4 + reg
#pragma unroll
  for (int m = 0; m < 4; ++m) {
    int row0 = bm + wr * 64 + m * 16 + l4 * 4;
#pragma unroll
    for (int r = 0; r < 4; ++r) {
      int row = row0 + r;
      if (row < M) {
#pragma unroll
        for (int n = 0; n < 4; ++n)
          C[(size_t)row * Nc + bn + wc * 64 + n * 16 + l15] = acc[m][n][r];
      }
    }
  }
}

// ---------------- CSR build ----------------
__global__ __launch_bounds__(256) void zero_i_k(int* __restrict__ p, int n) {
  int stride = gridDim.x * 256;
  for (int i = blockIdx.x * 256 + threadIdx.x; i < n; i += stride) p[i] = 0;
}

__global__ __launch_bounds__(256) void hist_k(const int* __restrict__ dsts,
                                              int* __restrict__ deg) {
  int e = blockIdx.x * 256 + threadIdx.x;
  if (e < NEDGES) atomicAdd(&deg[dsts[e]], 1);
}

__global__ __launch_bounds__(256) void bsum_k(const int* __restrict__ deg,
                                              int* __restrict__ bsum) {
  __shared__ int red[256];
  int t = threadIdx.x, i = blockIdx.x * 256 + t;
  red[t] = (i < NNODES) ? deg[i] : 0;
  __syncthreads();
#pragma unroll
  for (int off = 128; off > 0; off >>= 1) {
    if (t < off) red[t] += red[t + off];
    __syncthreads();
  }
  if (t == 0) bsum[blockIdx.x] = red[0];
}

__global__ __launch_bounds__(64) void bscan_k(const int* __restrict__ bsum,
                                              int* __restrict__ bscan) {
  if (threadIdx.x == 0) {
    int run = 0;
    for (int j = 0; j < NB; ++j) { bscan[j] = run; run += bsum[j]; }
  }
}

__global__ __launch_bounds__(256) void rowptr_k(const int* __restrict__ deg,
    const int* __restrict__ bscan, int* __restrict__ rowptr,
    int* __restrict__ cursor) {
  __shared__ int s[256];
  int t = threadIdx.x, b = blockIdx.x, i = b * 256 + t;
  int v = (i < NNODES) ? deg[i] : 0;
  s[t] = v;
  __syncthreads();
#pragma unroll
  for (int off = 1; off < 256; off <<= 1) {
    int y = (t >= off) ? s[t - off] : 0;
    __syncthreads();
    s[t] += y;
    __syncthreads();
  }
  if (i < NNODES) {
    int ex = bscan[b] + s[t] - v;
    rowptr[i] = ex;
    cursor[i] = ex;
  }
  if (b == 0 && t == 0) rowptr[NNODES] = NEDGES;
}

__global__ __launch_bounds__(256) void scatter_k(const int* __restrict__ srcs,
    const int* __restrict__ dsts, int* __restrict__ cursor,
    int* __restrict__ col) {
  int e = blockIdx.x * 256 + threadIdx.x;
  if (e < NEDGES) {
    int pos = atomicAdd(&cursor[dsts[e]], 1);
    col[pos] = srcs[e];
  }
}

// ---------------- fused layer-1: score+softmax+aggregate+relu(+b1)->bf16 ----------------
__global__ __launch_bounds__(256) void fused1_k(const int* __restrict__ rowptr,
    const int* __restrict__ col, const float* __restrict__ XL,
    const float* __restrict__ XR, const float* __restrict__ a1,
    const float* __restrict__ b1, short* __restrict__ Hb) {
  int d = blockIdx.x * 4 + (threadIdx.x >> 6);
  if (d >= NNODES) return;
  int lane = threadIdx.x & 63;
  float av[8], xr[8], acc[8];
#pragma unroll
  for (int t = 0; t < 8; ++t) {
    av[t] = a1[t * 64 + lane];
    xr[t] = XR[(size_t)d * D1 + t * 64 + lane];
    acc[t] = 0.f;
  }
  float den[4] = {0.f, 0.f, 0.f, 0.f};
  int beg = rowptr[d], end = rowptr[d + 1];
  for (int i = beg - 1; i < end; ++i) {   // i==beg-1 -> self loop
    int s = (i < beg) ? d : col[i];
    const float* xlp = XL + (size_t)s * D1;
    float xl[8];
#pragma unroll
    for (int t = 0; t < 8; ++t) xl[t] = xlp[t * 64 + lane];
    float part[4];
#pragma unroll
    for (int h = 0; h < 4; ++h) {
      float g0 = xl[2 * h] + xr[2 * h];
      float g1 = xl[2 * h + 1] + xr[2 * h + 1];
      g0 = g0 > 0.f ? g0 : NEG * g0;
      g1 = g1 > 0.f ? g1 : NEG * g1;
      part[h] = g0 * av[2 * h] + g1 * av[2 * h + 1];
    }
#pragma unroll
    for (int off = 32; off > 0; off >>= 1) {
#pragma unroll
      for (int h = 0; h < 4; ++h) part[h] += __shfl_xor(part[h], off);
    }
    float p[4];
#pragma unroll
    for (int h = 0; h < 4; ++h) { p[h] = __expf(part[h]); den[h] += p[h]; }
#pragma unroll
    for (int t = 0; t < 8; ++t) acc[t] = fmaf(p[t >> 1], xl[t], acc[t]);
  }
#pragma unroll
  for (int t = 0; t < 8; ++t) {
    float hv = acc[t] / den[t >> 1] + b1[t * 64 + lane];
    hv = hv > 0.f ? hv : 0.f;
    Hb[(size_t)d * D1 + t * 64 + lane] = f2bf(hv);
  }
}

// ---------------- fused layer-2 -> out (+b2) ----------------
__global__ __launch_bounds__(256) void fused2_k(const int* __restrict__ rowptr,
    const int* __restrict__ col, const float* __restrict__ XL,
    const float* __restrict__ XR, const float* __restrict__ a2,
    const float* __restrict__ b2, float* __restrict__ out) {
  int d = blockIdx.x * 4 + (threadIdx.x >> 6);
  if (d >= NNODES) return;
  int lane = threadIdx.x & 63;
  float av[4], xr[4], acc[4];
#pragma unroll
  for (int t = 0; t < 4; ++t) {
    av[t] = a2[t * 64 + lane];
    xr[t] = XR[(size_t)d * OUTC + t * 64 + lane];
    acc[t] = 0.f;
  }
  float den = 0.f;
  int beg = rowptr[d], end = rowptr[d + 1];
  for (int i = beg - 1; i < end; ++i) {
    int s = (i < beg) ? d : col[i];
    const float* xlp = XL + (size_t)s * OUTC;
    float xl[4];
#pragma unroll
    for (int t = 0; t < 4; ++t) xl[t] = xlp[t * 64 + lane];
    float part = 0.f;
#pragma unroll
    for (int t = 0; t < 4; ++t) {
      float g = xl[t] + xr[t];
      g = g > 0.f ? g : NEG * g;
      part = fmaf(g, av[t], part);
    }
#pragma unroll
    for (int off = 32; off > 0; off >>= 1) part += __shfl_xor(part, off);
    float p = __expf(part);
    den += p;
#pragma unroll
    for (int t = 0; t < 4; ++t) acc[t] = fmaf(p, xl[t], acc[t]);
  }
#pragma unroll
  for (int t = 0; t < 4; ++t)
    out[(size_t)d * OUTC + t * 64 + lane] = acc[t] / den + b2[t * 64 + lane];
}

extern "C" void kernel_launch(void* const* d_in, const int* in_sizes, int n_in,
                              void* d_out, int out_size, void* d_ws, size_t ws_size,
                              hipStream_t stream) {
  const float* x   = (const float*)d_in[0];
  const int*   ei  = (const int*)d_in[1];
  const float* W1l = (const float*)d_in[2];
  const float* W1r = (const float*)d_in[3];
  const float* a1  = (const float*)d_in[4];
  const float* b1  = (const float*)d_in[5];
  const float* W2l = (const float*)d_in[6];
  const float* W2r = (const float*)d_in[7];
  const float* a2  = (const float*)d_in[8];
  const float* b2  = (const float*)d_in[9];
  float* out = (float*)d_out;
  char* ws = (char*)d_ws;

  // ---- workspace layout (~208 MB, proven-safe budget) ----
  float* XL1   = (float*)(ws + 0);            // 102.4 MB
  float* XR1   = (float*)(ws + 102400000);    // 102.4 MB
  float* XL2   = (float*)(ws + 0);            // reuse (XL1 dead after fused1)
  float* XR2   = (float*)(ws + 51200000);
  short* WT1l  = (short*)(ws + 204800000);    // 262144 B each
  short* WT1r  = (short*)(ws + 205062144);
  short* WT2l  = (short*)(ws + 205324288);
  short* WT2r  = (short*)(ws + 205586432);
  int* rowptr  = (int*)(ws + 205848576);      // 200004 B
  int* cursor  = (int*)(ws + 206048640);      // 200000 B
  int* colv    = (int*)(ws + 206248640);      // 1.6 MB
  int* deg     = (int*)(ws + 207848640);      // 200000 B
  int* bsum    = (int*)(ws + 208048640);
  int* bscan   = (int*)(ws + 208049536);
  // d_out doubles as scratch until fused2: XB (25.6 MB), then Hb (51.2 MB)
  short* XB = (short*)d_out;
  short* Hb = (short*)d_out;

  const int* srcs = ei;
  const int* dsts = ei + NEDGES;

  dim3 blk(256);
  int eblk = (NEDGES + 255) / 256;
  int nblk4 = (NNODES + 3) / 4;

  // ---- CSR build (grouped by dst) ----
  zero_i_k<<<64, blk, 0, stream>>>(deg, NNODES);
  hist_k<<<eblk, blk, 0, stream>>>(dsts, deg);
  bsum_k<<<NB, blk, 0, stream>>>(deg, bsum);
  bscan_k<<<1, 64, 0, stream>>>(bsum, bscan);
  rowptr_k<<<NB, blk, 0, stream>>>(deg, bscan, rowptr, cursor);
  scatter_k<<<eblk, blk, 0, stream>>>(srcs, dsts, cursor, colv);

  // ---- bf16 prep: x and transposed weights ----
  cvt_x_k<<<(NNODES * INC) / 2048, blk, 0, stream>>>(x, XB);
  twb_k<<<dim3(D1 / 32, INC / 32), blk, 0, stream>>>(W1l, WT1l, INC, D1);
  twb_k<<<dim3(D1 / 32, INC / 32), blk, 0, stream>>>(W1r, WT1r, INC, D1);
  twb_k<<<dim3(OUTC / 32, D1 / 32), blk, 0, stream>>>(W2l, WT2l, D1, OUTC);
  twb_k<<<dim3(OUTC / 32, D1 / 32), blk, 0, stream>>>(W2r, WT2r, D1, OUTC);

  // ---- layer 1 linear transforms (bf16 MFMA) ----
  dim3 g1(D1 / 128, (NNODES + 127) / 128);
  gemm_bf16_k<<<g1, blk, 0, stream>>>(XB, WT1l, XL1, NNODES, INC, D1);
  gemm_bf16_k<<<g1, blk, 0, stream>>>(XB, WT1r, XR1, NNODES, INC, D1);

  // ---- layer 1 fused attention -> Hb = bf16(relu(.+b1)) in d_out ----
  fused1_k<<<nblk4, blk, 0, stream>>>(rowptr, colv, XL1, XR1, a1, b1, Hb);

  // ---- layer 2 linear transforms (bf16 MFMA) ----
  dim3 g2(OUTC / 128, (NNODES + 127) / 128);
  gemm_bf16_k<<<g2, blk, 0, stream>>>(Hb, WT2l, XL2, NNODES, D1, OUTC);
  gemm_bf16_k<<<g2, blk, 0, stream>>>(Hb, WT2r, XR2, NNODES, D1, OUTC);

  // ---- layer 2 fused attention -> out (+b2) ----
  fused2_k<<<nblk4, blk, 0, stream>>>(rowptr, colv, XL2, XR2, a2, b2, out);
}

// Round 9
// 494.374 us; speedup vs baseline: 5.0576x; 1.1567x over previous
//
#include <hip/hip_runtime.h>
#include <cstdint>
#include <cstddef>

#define NNODES 50000
#define NEDGES 400000
#define INC    256
#define D1     512        // HEADS*HID
#define OUTC   256
#define NEG    0.2f
#define NB     196        // ceil(NNODES/256)

typedef __attribute__((ext_vector_type(8))) short short8;
typedef __attribute__((ext_vector_type(4))) short bf16x4;
typedef __attribute__((ext_vector_type(4))) float f32x4;

__device__ inline short f2bf(float f) {
  union { float f; uint32_t u; } v; v.f = f;
  uint32_t r = (v.u + 0x7fffu + ((v.u >> 16) & 1u)) >> 16;
  return (short)(r & 0xffffu);
}
__device__ inline float bf2f(short s) {
  union { uint32_t u; float f; } v;
  v.u = ((uint32_t)(uint16_t)s) << 16;
  return v.f;
}

// ---------------- convert x -> bf16 (8 elems/thread) ----------------
__global__ __launch_bounds__(256) void cvt_x_k(const float* __restrict__ x,
                                               short* __restrict__ xb) {
  size_t base = ((size_t)blockIdx.x * 256 + threadIdx.x) * 8;
  f32x4 a = *(const f32x4*)&x[base];
  f32x4 b = *(const f32x4*)&x[base + 4];
  short8 o;
  o[0] = f2bf(a[0]); o[1] = f2bf(a[1]); o[2] = f2bf(a[2]); o[3] = f2bf(a[3]);
  o[4] = f2bf(b[0]); o[5] = f2bf(b[1]); o[6] = f2bf(b[2]); o[7] = f2bf(b[3]);
  *(short8*)&xb[base] = o;
}

// ---------------- transpose W[K][N] f32 -> WT[N][K] bf16 ----------------
__global__ __launch_bounds__(256) void twb_k(const float* __restrict__ W,
                                             short* __restrict__ WT,
                                             int K, int N) {
  __shared__ float tile[32][33];
  int tx = threadIdx.x & 31, ty = threadIdx.x >> 5;
  int n0 = blockIdx.x * 32, k0 = blockIdx.y * 32;
#pragma unroll
  for (int i = 0; i < 4; ++i)
    tile[ty + i * 8][tx] = W[(size_t)(k0 + ty + i * 8) * N + n0 + tx];
  __syncthreads();
#pragma unroll
  for (int i = 0; i < 4; ++i) {
    int n = ty + i * 8;
    WT[(size_t)(n0 + n) * K + k0 + tx] = f2bf(tile[tx][n]);
  }
}

// ---------------- bf16 MFMA GEMM: C[M,Nc] = A[M,K] @ BT[Nc,K]^T ----------------
// 128x128 tile, BK=64, 4 waves (2x2), 4x4 16x16 frags per wave.
#define LDT 72
template<bool BF16OUT>
__global__ __launch_bounds__(256) void gemm_bf16_k(const short* __restrict__ A,
    const short* __restrict__ BT, void* __restrict__ Cv, int M, int K, int Nc) {
  __shared__ short As[128 * LDT];
  __shared__ short Bs[128 * LDT];
  const int tid = threadIdx.x;
  const int lane = tid & 63, wave = tid >> 6;
  const int wr = wave >> 1, wc = wave & 1;
  const int l15 = lane & 15, l4 = lane >> 4;
  const int bm = blockIdx.y * 128, bn = blockIdx.x * 128;

  f32x4 zero4 = {0.f, 0.f, 0.f, 0.f};
  f32x4 acc[4][4];
#pragma unroll
  for (int m = 0; m < 4; ++m)
#pragma unroll
    for (int n = 0; n < 4; ++n) acc[m][n] = zero4;

  for (int k0 = 0; k0 < K; k0 += 64) {
#pragma unroll
    for (int i = 0; i < 4; ++i) {
      int q = tid + 256 * i;
      int row = q >> 3, kc = q & 7;
      short8 va = {0, 0, 0, 0, 0, 0, 0, 0};
      int gr = bm + row;
      if (gr < M) va = *(const short8*)&A[(size_t)gr * K + k0 + kc * 8];
      *(short8*)&As[row * LDT + kc * 8] = va;
      short8 vb = *(const short8*)&BT[(size_t)(bn + row) * K + k0 + kc * 8];
      *(short8*)&Bs[row * LDT + kc * 8] = vb;
    }
    __syncthreads();
    short8 af[4][2], bf[4][2];
#pragma unroll
    for (int m = 0; m < 4; ++m)
#pragma unroll
      for (int kk = 0; kk < 2; ++kk)
        af[m][kk] = *(const short8*)&As[(wr * 64 + m * 16 + l15) * LDT + kk * 32 + l4 * 8];
#pragma unroll
    for (int n = 0; n < 4; ++n)
#pragma unroll
      for (int kk = 0; kk < 2; ++kk)
        bf[n][kk] = *(const short8*)&Bs[(wc * 64 + n * 16 + l15) * LDT + kk * 32 + l4 * 8];
#pragma unroll
    for (int kk = 0; kk < 2; ++kk)
#pragma unroll
      for (int m = 0; m < 4; ++m)
#pragma unroll
        for (int n = 0; n < 4; ++n)
          acc[m][n] = __builtin_amdgcn_mfma_f32_16x16x32_bf16(
              af[m][kk], bf[n][kk], acc[m][n], 0, 0, 0);
    __syncthreads();
  }
  // C/D layout (m89-verified): col = lane&15, row = (lane>>4)*4 + reg
#pragma unroll
  for (int m = 0; m < 4; ++m) {
    int row0 = bm + wr * 64 + m * 16 + l4 * 4;
#pragma unroll
    for (int r = 0; r < 4; ++r) {
      int row = row0 + r;
      if (row < M) {
#pragma unroll
        for (int n = 0; n < 4; ++n) {
          size_t idx = (size_t)row * Nc + bn + wc * 64 + n * 16 + l15;
          if (BF16OUT) ((short*)Cv)[idx] = f2bf(acc[m][n][r]);
          else         ((float*)Cv)[idx] = acc[m][n][r];
        }
      }
    }
  }
}

// ---------------- CSR build ----------------
__global__ __launch_bounds__(256) void zero_i_k(int* __restrict__ p, int n) {
  int stride = gridDim.x * 256;
  for (int i = blockIdx.x * 256 + threadIdx.x; i < n; i += stride) p[i] = 0;
}

__global__ __launch_bounds__(256) void hist_k(const int* __restrict__ dsts,
                                              int* __restrict__ deg) {
  int e = blockIdx.x * 256 + threadIdx.x;
  if (e < NEDGES) atomicAdd(&deg[dsts[e]], 1);
}

__global__ __launch_bounds__(256) void bsum_k(const int* __restrict__ deg,
                                              int* __restrict__ bsum) {
  __shared__ int red[256];
  int t = threadIdx.x, i = blockIdx.x * 256 + t;
  red[t] = (i < NNODES) ? deg[i] : 0;
  __syncthreads();
#pragma unroll
  for (int off = 128; off > 0; off >>= 1) {
    if (t < off) red[t] += red[t + off];
    __syncthreads();
  }
  if (t == 0) bsum[blockIdx.x] = red[0];
}

__global__ __launch_bounds__(64) void bscan_k(const int* __restrict__ bsum,
                                              int* __restrict__ bscan) {
  if (threadIdx.x == 0) {
    int run = 0;
    for (int j = 0; j < NB; ++j) { bscan[j] = run; run += bsum[j]; }
  }
}

__global__ __launch_bounds__(256) void rowptr_k(const int* __restrict__ deg,
    const int* __restrict__ bscan, int* __restrict__ rowptr,
    int* __restrict__ cursor) {
  __shared__ int s[256];
  int t = threadIdx.x, b = blockIdx.x, i = b * 256 + t;
  int v = (i < NNODES) ? deg[i] : 0;
  s[t] = v;
  __syncthreads();
#pragma unroll
  for (int off = 1; off < 256; off <<= 1) {
    int y = (t >= off) ? s[t - off] : 0;
    __syncthreads();
    s[t] += y;
    __syncthreads();
  }
  if (i < NNODES) {
    int ex = bscan[b] + s[t] - v;
    rowptr[i] = ex;
    cursor[i] = ex;
  }
  if (b == 0 && t == 0) rowptr[NNODES] = NEDGES;
}

__global__ __launch_bounds__(256) void scatter_k(const int* __restrict__ srcs,
    const int* __restrict__ dsts, int* __restrict__ cursor,
    int* __restrict__ col) {
  int e = blockIdx.x * 256 + threadIdx.x;
  if (e < NEDGES) {
    int pos = atomicAdd(&cursor[dsts[e]], 1);
    col[pos] = srcs[e];
  }
}

// ---------------- fused layer-1: lane owns channels lane*8..+7, head = lane>>4 ----------------
__global__ __launch_bounds__(256) void fused1_k(const int* __restrict__ rowptr,
    const int* __restrict__ col, const short* __restrict__ XLb,
    const float* __restrict__ XR, const float* __restrict__ a1,
    const float* __restrict__ b1, short* __restrict__ Hb) {
  int d = blockIdx.x * 4 + (threadIdx.x >> 6);
  if (d >= NNODES) return;
  int lane = threadIdx.x & 63;
  int c0 = lane * 8;
  float av[8], xr[8], acc[8];
#pragma unroll
  for (int t = 0; t < 8; ++t) {
    av[t] = a1[c0 + t];
    xr[t] = XR[(size_t)d * D1 + c0 + t];
    acc[t] = 0.f;
  }
  float den = 0.f;
  int beg = rowptr[d], end = rowptr[d + 1];
  for (int i = beg - 1; i < end; ++i) {   // i==beg-1 -> self loop
    int s = (i < beg) ? d : col[i];
    short8 v = *(const short8*)&XLb[(size_t)s * D1 + c0];
    float xl[8];
#pragma unroll
    for (int t = 0; t < 8; ++t) xl[t] = bf2f(v[t]);
    float part = 0.f;
#pragma unroll
    for (int t = 0; t < 8; ++t) {
      float g = xl[t] + xr[t];
      g = g > 0.f ? g : NEG * g;
      part = fmaf(g, av[t], part);
    }
    // reduce within 16-lane head group (128 channels/head)
    part += __shfl_xor(part, 1);
    part += __shfl_xor(part, 2);
    part += __shfl_xor(part, 4);
    part += __shfl_xor(part, 8);
    float p = __expf(part);
    den += p;
#pragma unroll
    for (int t = 0; t < 8; ++t) acc[t] = fmaf(p, xl[t], acc[t]);
  }
  short8 o;
#pragma unroll
  for (int t = 0; t < 8; ++t) {
    float hv = acc[t] / den + b1[c0 + t];
    hv = hv > 0.f ? hv : 0.f;
    o[t] = f2bf(hv);
  }
  *(short8*)&Hb[(size_t)d * D1 + c0] = o;
}

// ---------------- fused layer-2: lane owns channels lane*4..+3, 1 head ----------------
__global__ __launch_bounds__(256) void fused2_k(const int* __restrict__ rowptr,
    const int* __restrict__ col, const short* __restrict__ XLb,
    const float* __restrict__ XR, const float* __restrict__ a2,
    const float* __restrict__ b2, float* __restrict__ out) {
  int d = blockIdx.x * 4 + (threadIdx.x >> 6);
  if (d >= NNODES) return;
  int lane = threadIdx.x & 63;
  int c0 = lane * 4;
  float av[4], xr[4], acc[4];
#pragma unroll
  for (int t = 0; t < 4; ++t) {
    av[t] = a2[c0 + t];
    xr[t] = XR[(size_t)d * OUTC + c0 + t];
    acc[t] = 0.f;
  }
  float den = 0.f;
  int beg = rowptr[d], end = rowptr[d + 1];
  for (int i = beg - 1; i < end; ++i) {
    int s = (i < beg) ? d : col[i];
    bf16x4 v = *(const bf16x4*)&XLb[(size_t)s * OUTC + c0];
    float xl[4];
#pragma unroll
    for (int t = 0; t < 4; ++t) xl[t] = bf2f(v[t]);
    float part = 0.f;
#pragma unroll
    for (int t = 0; t < 4; ++t) {
      float g = xl[t] + xr[t];
      g = g > 0.f ? g : NEG * g;
      part = fmaf(g, av[t], part);
    }
#pragma unroll
    for (int off = 1; off < 64; off <<= 1) part += __shfl_xor(part, off);
    float p = __expf(part);
    den += p;
#pragma unroll
    for (int t = 0; t < 4; ++t) acc[t] = fmaf(p, xl[t], acc[t]);
  }
  f32x4 o;
#pragma unroll
  for (int t = 0; t < 4; ++t) o[t] = acc[t] / den + b2[c0 + t];
  *(f32x4*)&out[(size_t)d * OUTC + c0] = o;
}

extern "C" void kernel_launch(void* const* d_in, const int* in_sizes, int n_in,
                              void* d_out, int out_size, void* d_ws, size_t ws_size,
                              hipStream_t stream) {
  const float* x   = (const float*)d_in[0];
  const int*   ei  = (const int*)d_in[1];
  const float* W1l = (const float*)d_in[2];
  const float* W1r = (const float*)d_in[3];
  const float* a1  = (const float*)d_in[4];
  const float* b1  = (const float*)d_in[5];
  const float* W2l = (const float*)d_in[6];
  const float* W2r = (const float*)d_in[7];
  const float* a2  = (const float*)d_in[8];
  const float* b2  = (const float*)d_in[9];
  float* out = (float*)d_out;
  char* ws = (char*)d_ws;

  // ---- workspace layout (~157 MB high-water) ----
  short* XL1b  = (short*)(ws + 0);            // 51.2 MB bf16
  float* XR1   = (float*)(ws + 51200000);     // 102.4 MB f32 (ends 153.6 MB)
  short* XL2b  = (short*)(ws + 0);            // 25.6 MB (XL1b dead after fused1)
  float* XR2   = (float*)(ws + 25600000);     // 51.2 MB (XR1 dead after fused1)
  short* WT1l  = (short*)(ws + 153600000);    // 262144 B each
  short* WT1r  = (short*)(ws + 153862144);
  short* WT2l  = (short*)(ws + 154124288);
  short* WT2r  = (short*)(ws + 154386432);
  int* rowptr  = (int*)(ws + 154648576);      // 200004 B
  int* cursor  = (int*)(ws + 154848640);      // 200000 B
  int* colv    = (int*)(ws + 155048640);      // 1.6 MB
  int* deg     = (int*)(ws + 156648640);      // 200000 B
  int* bsum    = (int*)(ws + 156848640);
  int* bscan   = (int*)(ws + 156849536);
  // d_out doubles as scratch: XB (25.6 MB) then Hb (51.2 MB = out_size)
  short* XB = (short*)d_out;
  short* Hb = (short*)d_out;

  const int* srcs = ei;
  const int* dsts = ei + NEDGES;

  dim3 blk(256);
  int eblk = (NEDGES + 255) / 256;
  int nblk4 = (NNODES + 3) / 4;

  // ---- CSR build (grouped by dst) ----
  zero_i_k<<<64, blk, 0, stream>>>(deg, NNODES);
  hist_k<<<eblk, blk, 0, stream>>>(dsts, deg);
  bsum_k<<<NB, blk, 0, stream>>>(deg, bsum);
  bscan_k<<<1, 64, 0, stream>>>(bsum, bscan);
  rowptr_k<<<NB, blk, 0, stream>>>(deg, bscan, rowptr, cursor);
  scatter_k<<<eblk, blk, 0, stream>>>(srcs, dsts, cursor, colv);

  // ---- bf16 prep: x and transposed weights ----
  cvt_x_k<<<(NNODES * INC) / 2048, blk, 0, stream>>>(x, XB);
  twb_k<<<dim3(D1 / 32, INC / 32), blk, 0, stream>>>(W1l, WT1l, INC, D1);
  twb_k<<<dim3(D1 / 32, INC / 32), blk, 0, stream>>>(W1r, WT1r, INC, D1);
  twb_k<<<dim3(OUTC / 32, D1 / 32), blk, 0, stream>>>(W2l, WT2l, D1, OUTC);
  twb_k<<<dim3(OUTC / 32, D1 / 32), blk, 0, stream>>>(W2r, WT2r, D1, OUTC);

  // ---- layer 1 linear transforms: XL bf16 out, XR f32 out ----
  dim3 g1(D1 / 128, (NNODES + 127) / 128);
  gemm_bf16_k<true ><<<g1, blk, 0, stream>>>(XB, WT1l, XL1b, NNODES, INC, D1);
  gemm_bf16_k<false><<<g1, blk, 0, stream>>>(XB, WT1r, XR1, NNODES, INC, D1);

  // ---- layer 1 fused attention -> Hb = bf16(relu(.+b1)) in d_out ----
  fused1_k<<<nblk4, blk, 0, stream>>>(rowptr, colv, XL1b, XR1, a1, b1, Hb);

  // ---- layer 2 linear transforms ----
  dim3 g2(OUTC / 128, (NNODES + 127) / 128);
  gemm_bf16_k<true ><<<g2, blk, 0, stream>>>(Hb, WT2l, XL2b, NNODES, D1, OUTC);
  gemm_bf16_k<false><<<g2, blk, 0, stream>>>(Hb, WT2r, XR2, NNODES, D1, OUTC);

  // ---- layer 2 fused attention -> out (+b2) ----
  fused2_k<<<nblk4, blk, 0, stream>>>(rowptr, colv, XL2b, XR2, a2, b2, out);
}

// Round 10
// 420.522 us; speedup vs baseline: 5.9458x; 1.1756x over previous
//
#include <hip/hip_runtime.h>
#include <cstdint>
#include <cstddef>

#define NNODES 50000
#define NEDGES 400000
#define INC    256
#define D1     512        // HEADS*HID
#define OUTC   256
#define NEG    0.2f
#define NB     196        // ceil(NNODES/256)

typedef __attribute__((ext_vector_type(8))) short short8;
typedef __attribute__((ext_vector_type(4))) short bf16x4;
typedef __attribute__((ext_vector_type(4))) float f32x4;

__device__ inline short f2bf(float f) {
  union { float f; uint32_t u; } v; v.f = f;
  uint32_t r = (v.u + 0x7fffu + ((v.u >> 16) & 1u)) >> 16;
  return (short)(r & 0xffffu);
}
__device__ inline float bf2f(short s) {
  union { uint32_t u; float f; } v;
  v.u = ((uint32_t)(uint16_t)s) << 16;
  return v.f;
}

// ---------------- convert x -> bf16 (8 elems/thread) ----------------
__global__ __launch_bounds__(256) void cvt_x_k(const float* __restrict__ x,
                                               short* __restrict__ xb) {
  size_t base = ((size_t)blockIdx.x * 256 + threadIdx.x) * 8;
  f32x4 a = *(const f32x4*)&x[base];
  f32x4 b = *(const f32x4*)&x[base + 4];
  short8 o;
  o[0] = f2bf(a[0]); o[1] = f2bf(a[1]); o[2] = f2bf(a[2]); o[3] = f2bf(a[3]);
  o[4] = f2bf(b[0]); o[5] = f2bf(b[1]); o[6] = f2bf(b[2]); o[7] = f2bf(b[3]);
  *(short8*)&xb[base] = o;
}

// ---------------- transpose W[K][N] f32 -> WT[N][K] bf16 ----------------
__global__ __launch_bounds__(256) void twb_k(const float* __restrict__ W,
                                             short* __restrict__ WT,
                                             int K, int N) {
  __shared__ float tile[32][33];
  int tx = threadIdx.x & 31, ty = threadIdx.x >> 5;
  int n0 = blockIdx.x * 32, k0 = blockIdx.y * 32;
#pragma unroll
  for (int i = 0; i < 4; ++i)
    tile[ty + i * 8][tx] = W[(size_t)(k0 + ty + i * 8) * N + n0 + tx];
  __syncthreads();
#pragma unroll
  for (int i = 0; i < 4; ++i) {
    int n = ty + i * 8;
    WT[(size_t)(n0 + n) * K + k0 + tx] = f2bf(tile[tx][n]);
  }
}

// ---------------- bf16 MFMA GEMM: C[M,Nc] = A[M,K] @ BT[Nc,K]^T, bf16 out ----------------
// 128x128 tile, BK=64, 4 waves (2x2), 4x4 16x16 frags per wave.
#define LDT 72
__global__ __launch_bounds__(256) void gemm_bf16_k(const short* __restrict__ A,
    const short* __restrict__ BT, short* __restrict__ C, int M, int K, int Nc) {
  __shared__ short As[128 * LDT];
  __shared__ short Bs[128 * LDT];
  const int tid = threadIdx.x;
  const int lane = tid & 63, wave = tid >> 6;
  const int wr = wave >> 1, wc = wave & 1;
  const int l15 = lane & 15, l4 = lane >> 4;
  const int bm = blockIdx.y * 128, bn = blockIdx.x * 128;

  f32x4 zero4 = {0.f, 0.f, 0.f, 0.f};
  f32x4 acc[4][4];
#pragma unroll
  for (int m = 0; m < 4; ++m)
#pragma unroll
    for (int n = 0; n < 4; ++n) acc[m][n] = zero4;

  for (int k0 = 0; k0 < K; k0 += 64) {
#pragma unroll
    for (int i = 0; i < 4; ++i) {
      int q = tid + 256 * i;
      int row = q >> 3, kc = q & 7;
      short8 va = {0, 0, 0, 0, 0, 0, 0, 0};
      int gr = bm + row;
      if (gr < M) va = *(const short8*)&A[(size_t)gr * K + k0 + kc * 8];
      *(short8*)&As[row * LDT + kc * 8] = va;
      short8 vb = *(const short8*)&BT[(size_t)(bn + row) * K + k0 + kc * 8];
      *(short8*)&Bs[row * LDT + kc * 8] = vb;
    }
    __syncthreads();
    short8 af[4][2], bf[4][2];
#pragma unroll
    for (int m = 0; m < 4; ++m)
#pragma unroll
      for (int kk = 0; kk < 2; ++kk)
        af[m][kk] = *(const short8*)&As[(wr * 64 + m * 16 + l15) * LDT + kk * 32 + l4 * 8];
#pragma unroll
    for (int n = 0; n < 4; ++n)
#pragma unroll
      for (int kk = 0; kk < 2; ++kk)
        bf[n][kk] = *(const short8*)&Bs[(wc * 64 + n * 16 + l15) * LDT + kk * 32 + l4 * 8];
#pragma unroll
    for (int kk = 0; kk < 2; ++kk)
#pragma unroll
      for (int m = 0; m < 4; ++m)
#pragma unroll
        for (int n = 0; n < 4; ++n)
          acc[m][n] = __builtin_amdgcn_mfma_f32_16x16x32_bf16(
              af[m][kk], bf[n][kk], acc[m][n], 0, 0, 0);
    __syncthreads();
  }
  // C/D layout (m89-verified): col = lane&15, row = (lane>>4)*4 + reg
#pragma unroll
  for (int m = 0; m < 4; ++m) {
    int row0 = bm + wr * 64 + m * 16 + l4 * 4;
#pragma unroll
    for (int r = 0; r < 4; ++r) {
      int row = row0 + r;
      if (row < M) {
#pragma unroll
        for (int n = 0; n < 4; ++n)
          C[(size_t)row * Nc + bn + wc * 64 + n * 16 + l15] = f2bf(acc[m][n][r]);
      }
    }
  }
}

// ---------------- CSR build ----------------
__global__ __launch_bounds__(256) void zero_i_k(int* __restrict__ p, int n) {
  int stride = gridDim.x * 256;
  for (int i = blockIdx.x * 256 + threadIdx.x; i < n; i += stride) p[i] = 0;
}

__global__ __launch_bounds__(256) void hist_k(const int* __restrict__ dsts,
                                              int* __restrict__ deg) {
  int e = blockIdx.x * 256 + threadIdx.x;
  if (e < NEDGES) atomicAdd(&deg[dsts[e]], 1);
}

__global__ __launch_bounds__(256) void bsum_k(const int* __restrict__ deg,
                                              int* __restrict__ bsum) {
  __shared__ int red[256];
  int t = threadIdx.x, i = blockIdx.x * 256 + t;
  red[t] = (i < NNODES) ? deg[i] : 0;
  __syncthreads();
#pragma unroll
  for (int off = 128; off > 0; off >>= 1) {
    if (t < off) red[t] += red[t + off];
    __syncthreads();
  }
  if (t == 0) bsum[blockIdx.x] = red[0];
}

__global__ __launch_bounds__(64) void bscan_k(const int* __restrict__ bsum,
                                              int* __restrict__ bscan) {
  if (threadIdx.x == 0) {
    int run = 0;
    for (int j = 0; j < NB; ++j) { bscan[j] = run; run += bsum[j]; }
  }
}

__global__ __launch_bounds__(256) void rowptr_k(const int* __restrict__ deg,
    const int* __restrict__ bscan, int* __restrict__ rowptr,
    int* __restrict__ cursor) {
  __shared__ int s[256];
  int t = threadIdx.x, b = blockIdx.x, i = b * 256 + t;
  int v = (i < NNODES) ? deg[i] : 0;
  s[t] = v;
  __syncthreads();
#pragma unroll
  for (int off = 1; off < 256; off <<= 1) {
    int y = (t >= off) ? s[t - off] : 0;
    __syncthreads();
    s[t] += y;
    __syncthreads();
  }
  if (i < NNODES) {
    int ex = bscan[b] + s[t] - v;
    rowptr[i] = ex;
    cursor[i] = ex;
  }
  if (b == 0 && t == 0) rowptr[NNODES] = NEDGES;
}

__global__ __launch_bounds__(256) void scatter_k(const int* __restrict__ srcs,
    const int* __restrict__ dsts, int* __restrict__ cursor,
    int* __restrict__ col) {
  int e = blockIdx.x * 256 + threadIdx.x;
  if (e < NEDGES) {
    int pos = atomicAdd(&cursor[dsts[e]], 1);
    col[pos] = srcs[e];
  }
}

// ---------------- fused layer-1 ----------------
// X1b[d] row = [xl(512) | xr(512)] bf16. lane owns channels lane*8..+7, head = lane>>4.
__global__ __launch_bounds__(256) void fused1_k(const int* __restrict__ rowptr,
    const int* __restrict__ col, const short* __restrict__ X1b,
    const float* __restrict__ a1, const float* __restrict__ b1,
    short* __restrict__ Hb) {
  int d = blockIdx.x * 4 + (threadIdx.x >> 6);
  if (d >= NNODES) return;
  int lane = threadIdx.x & 63;
  int c0 = lane * 8;
  const size_t drow = (size_t)d * 1024;
  float av[8], xr[8], acc[8];
  short8 vself = *(const short8*)&X1b[drow + c0];
  short8 vxr   = *(const short8*)&X1b[drow + 512 + c0];
#pragma unroll
  for (int t = 0; t < 8; ++t) {
    av[t] = a1[c0 + t];
    xr[t] = bf2f(vxr[t]);
    acc[t] = 0.f;
  }
  float den = 0.f;
  {  // self loop
    float xl[8], part = 0.f;
#pragma unroll
    for (int t = 0; t < 8; ++t) {
      xl[t] = bf2f(vself[t]);
      float g = xl[t] + xr[t];
      g = fmaxf(g, NEG * g);
      part = fmaf(g, av[t], part);
    }
    part += __shfl_xor(part, 1); part += __shfl_xor(part, 2);
    part += __shfl_xor(part, 4); part += __shfl_xor(part, 8);
    float p = __expf(part);
    den += p;
#pragma unroll
    for (int t = 0; t < 8; ++t) acc[t] = fmaf(p, xl[t], acc[t]);
  }
  int beg = rowptr[d], end = rowptr[d + 1];
  int i = beg;
  for (; i + 1 < end; i += 2) {
    int s0 = col[i], s1 = col[i + 1];
    short8 v0 = *(const short8*)&X1b[(size_t)s0 * 1024 + c0];
    short8 v1 = *(const short8*)&X1b[(size_t)s1 * 1024 + c0];
    float xl0[8], xl1[8], p0 = 0.f, p1 = 0.f;
#pragma unroll
    for (int t = 0; t < 8; ++t) {
      xl0[t] = bf2f(v0[t]);
      float g0 = xl0[t] + xr[t]; g0 = fmaxf(g0, NEG * g0); p0 = fmaf(g0, av[t], p0);
      xl1[t] = bf2f(v1[t]);
      float g1 = xl1[t] + xr[t]; g1 = fmaxf(g1, NEG * g1); p1 = fmaf(g1, av[t], p1);
    }
    p0 += __shfl_xor(p0, 1); p1 += __shfl_xor(p1, 1);
    p0 += __shfl_xor(p0, 2); p1 += __shfl_xor(p1, 2);
    p0 += __shfl_xor(p0, 4); p1 += __shfl_xor(p1, 4);
    p0 += __shfl_xor(p0, 8); p1 += __shfl_xor(p1, 8);
    float e0 = __expf(p0), e1 = __expf(p1);
    den += e0 + e1;
#pragma unroll
    for (int t = 0; t < 8; ++t) {
      acc[t] = fmaf(e0, xl0[t], acc[t]);
      acc[t] = fmaf(e1, xl1[t], acc[t]);
    }
  }
  if (i < end) {
    int s = col[i];
    short8 v = *(const short8*)&X1b[(size_t)s * 1024 + c0];
    float xl[8], part = 0.f;
#pragma unroll
    for (int t = 0; t < 8; ++t) {
      xl[t] = bf2f(v[t]);
      float g = xl[t] + xr[t];
      g = fmaxf(g, NEG * g);
      part = fmaf(g, av[t], part);
    }
    part += __shfl_xor(part, 1); part += __shfl_xor(part, 2);
    part += __shfl_xor(part, 4); part += __shfl_xor(part, 8);
    float p = __expf(part);
    den += p;
#pragma unroll
    for (int t = 0; t < 8; ++t) acc[t] = fmaf(p, xl[t], acc[t]);
  }
  short8 o;
#pragma unroll
  for (int t = 0; t < 8; ++t) {
    float hv = acc[t] / den + b1[c0 + t];
    o[t] = f2bf(fmaxf(hv, 0.f));
  }
  *(short8*)&Hb[(size_t)d * D1 + c0] = o;
}

// ---------------- fused layer-2 ----------------
// X2b[d] row = [xl(256) | xr(256)] bf16. lane owns channels lane*4..+3, 1 head.
__global__ __launch_bounds__(256) void fused2_k(const int* __restrict__ rowptr,
    const int* __restrict__ col, const short* __restrict__ X2b,
    const float* __restrict__ a2, const float* __restrict__ b2,
    float* __restrict__ out) {
  int d = blockIdx.x * 4 + (threadIdx.x >> 6);
  if (d >= NNODES) return;
  int lane = threadIdx.x & 63;
  int c0 = lane * 4;
  const size_t drow = (size_t)d * 512;
  float av[4], xr[4], acc[4];
  bf16x4 vself = *(const bf16x4*)&X2b[drow + c0];
  bf16x4 vxr   = *(const bf16x4*)&X2b[drow + 256 + c0];
#pragma unroll
  for (int t = 0; t < 4; ++t) {
    av[t] = a2[c0 + t];
    xr[t] = bf2f(vxr[t]);
    acc[t] = 0.f;
  }
  float den = 0.f;
  {  // self loop
    float xl[4], part = 0.f;
#pragma unroll
    for (int t = 0; t < 4; ++t) {
      xl[t] = bf2f(vself[t]);
      float g = xl[t] + xr[t];
      g = fmaxf(g, NEG * g);
      part = fmaf(g, av[t], part);
    }
#pragma unroll
    for (int off = 1; off < 64; off <<= 1) part += __shfl_xor(part, off);
    float p = __expf(part);
    den += p;
#pragma unroll
    for (int t = 0; t < 4; ++t) acc[t] = fmaf(p, xl[t], acc[t]);
  }
  int beg = rowptr[d], end = rowptr[d + 1];
  int i = beg;
  for (; i + 1 < end; i += 2) {
    int s0 = col[i], s1 = col[i + 1];
    bf16x4 v0 = *(const bf16x4*)&X2b[(size_t)s0 * 512 + c0];
    bf16x4 v1 = *(const bf16x4*)&X2b[(size_t)s1 * 512 + c0];
    float xl0[4], xl1[4], p0 = 0.f, p1 = 0.f;
#pragma unroll
    for (int t = 0; t < 4; ++t) {
      xl0[t] = bf2f(v0[t]);
      float g0 = xl0[t] + xr[t]; g0 = fmaxf(g0, NEG * g0); p0 = fmaf(g0, av[t], p0);
      xl1[t] = bf2f(v1[t]);
      float g1 = xl1[t] + xr[t]; g1 = fmaxf(g1, NEG * g1); p1 = fmaf(g1, av[t], p1);
    }
#pragma unroll
    for (int off = 1; off < 64; off <<= 1) {
      p0 += __shfl_xor(p0, off);
      p1 += __shfl_xor(p1, off);
    }
    float e0 = __expf(p0), e1 = __expf(p1);
    den += e0 + e1;
#pragma unroll
    for (int t = 0; t < 4; ++t) {
      acc[t] = fmaf(e0, xl0[t], acc[t]);
      acc[t] = fmaf(e1, xl1[t], acc[t]);
    }
  }
  if (i < end) {
    int s = col[i];
    bf16x4 v = *(const bf16x4*)&X2b[(size_t)s * 512 + c0];
    float xl[4], part = 0.f;
#pragma unroll
    for (int t = 0; t < 4; ++t) {
      xl[t] = bf2f(v[t]);
      float g = xl[t] + xr[t];
      g = fmaxf(g, NEG * g);
      part = fmaf(g, av[t], part);
    }
#pragma unroll
    for (int off = 1; off < 64; off <<= 1) part += __shfl_xor(part, off);
    float p = __expf(part);
    den += p;
#pragma unroll
    for (int t = 0; t < 4; ++t) acc[t] = fmaf(p, xl[t], acc[t]);
  }
  f32x4 o;
#pragma unroll
  for (int t = 0; t < 4; ++t) o[t] = acc[t] / den + b2[c0 + t];
  *(f32x4*)&out[(size_t)d * OUTC + c0] = o;
}

extern "C" void kernel_launch(void* const* d_in, const int* in_sizes, int n_in,
                              void* d_out, int out_size, void* d_ws, size_t ws_size,
                              hipStream_t stream) {
  const float* x   = (const float*)d_in[0];
  const int*   ei  = (const int*)d_in[1];
  const float* W1l = (const float*)d_in[2];
  const float* W1r = (const float*)d_in[3];
  const float* a1  = (const float*)d_in[4];
  const float* b1  = (const float*)d_in[5];
  const float* W2l = (const float*)d_in[6];
  const float* W2r = (const float*)d_in[7];
  const float* a2  = (const float*)d_in[8];
  const float* b2  = (const float*)d_in[9];
  float* out = (float*)d_out;
  char* ws = (char*)d_ws;

  // ---- workspace layout (~106 MB high-water) ----
  short* X1b   = (short*)(ws + 0);            // 50000x1024 bf16 = 102.4 MB
  short* X2b   = (short*)(ws + 0);            // 50000x512 bf16 = 51.2 MB (reuse after fused1)
  short* WT1   = (short*)(ws + 102400000);    // 1024x256 bf16 = 524288 B
  short* WT2   = (short*)(ws + 102924288);    // 512x512 bf16 = 524288 B
  int* rowptr  = (int*)(ws + 103448576);      // 200004 B
  int* cursor  = (int*)(ws + 103648640);      // 200000 B
  int* colv    = (int*)(ws + 103848640);      // 1.6 MB
  int* deg     = (int*)(ws + 105448640);      // 200000 B
  int* bsum    = (int*)(ws + 105648640);
  int* bscan   = (int*)(ws + 105649536);
  // d_out doubles as scratch: XB (25.6 MB) then Hb (51.2 MB = out_size)
  short* XB = (short*)d_out;
  short* Hb = (short*)d_out;

  const int* srcs = ei;
  const int* dsts = ei + NEDGES;

  dim3 blk(256);
  int eblk = (NEDGES + 255) / 256;
  int nblk4 = (NNODES + 3) / 4;

  // ---- CSR build (grouped by dst) ----
  zero_i_k<<<64, blk, 0, stream>>>(deg, NNODES);
  hist_k<<<eblk, blk, 0, stream>>>(dsts, deg);
  bsum_k<<<NB, blk, 0, stream>>>(deg, bsum);
  bscan_k<<<1, 64, 0, stream>>>(bsum, bscan);
  rowptr_k<<<NB, blk, 0, stream>>>(deg, bscan, rowptr, cursor);
  scatter_k<<<eblk, blk, 0, stream>>>(srcs, dsts, cursor, colv);

  // ---- bf16 prep: x and concatenated transposed weights ----
  cvt_x_k<<<(NNODES * INC) / 2048, blk, 0, stream>>>(x, XB);
  twb_k<<<dim3(D1 / 32, INC / 32), blk, 0, stream>>>(W1l, WT1, INC, D1);
  twb_k<<<dim3(D1 / 32, INC / 32), blk, 0, stream>>>(W1r, WT1 + 512 * 256, INC, D1);
  twb_k<<<dim3(OUTC / 32, D1 / 32), blk, 0, stream>>>(W2l, WT2, D1, OUTC);
  twb_k<<<dim3(OUTC / 32, D1 / 32), blk, 0, stream>>>(W2r, WT2 + 256 * 512, D1, OUTC);

  // ---- layer 1: one merged GEMM -> X1b = [xl | xr] bf16 ----
  gemm_bf16_k<<<dim3(1024 / 128, (NNODES + 127) / 128), blk, 0, stream>>>(
      XB, WT1, X1b, NNODES, INC, 1024);

  // ---- layer 1 fused attention -> Hb = bf16(relu(.+b1)) in d_out ----
  fused1_k<<<nblk4, blk, 0, stream>>>(rowptr, colv, X1b, a1, b1, Hb);

  // ---- layer 2: one merged GEMM -> X2b = [xl | xr] bf16 ----
  gemm_bf16_k<<<dim3(512 / 128, (NNODES + 127) / 128), blk, 0, stream>>>(
      Hb, WT2, X2b, NNODES, D1, 512);

  // ---- layer 2 fused attention -> out (+b2) ----
  fused2_k<<<nblk4, blk, 0, stream>>>(rowptr, colv, X2b, a2, b2, out);
}

// Round 11
// 412.898 us; speedup vs baseline: 6.0556x; 1.0185x over previous
//
#include <hip/hip_runtime.h>
#include <cstdint>
#include <cstddef>

#define NNODES 50000
#define NEDGES 400000
#define INC    256
#define D1     512        // HEADS*HID
#define OUTC   256
#define NEG    0.2f
#define NB     196        // ceil(NNODES/256)

typedef __attribute__((ext_vector_type(8))) short short8;
typedef __attribute__((ext_vector_type(4))) short bf16x4;
typedef __attribute__((ext_vector_type(4))) float f32x4;

__device__ inline short f2bf(float f) {
  union { float f; uint32_t u; } v; v.f = f;
  uint32_t r = (v.u + 0x7fffu + ((v.u >> 16) & 1u)) >> 16;
  return (short)(r & 0xffffu);
}
__device__ inline float bf2f(short s) {
  union { uint32_t u; float f; } v;
  v.u = ((uint32_t)(uint16_t)s) << 16;
  return v.f;
}

// ---------------- convert x -> bf16 (8 elems/thread) ----------------
__global__ __launch_bounds__(256) void cvt_x_k(const float* __restrict__ x,
                                               short* __restrict__ xb) {
  size_t base = ((size_t)blockIdx.x * 256 + threadIdx.x) * 8;
  f32x4 a = *(const f32x4*)&x[base];
  f32x4 b = *(const f32x4*)&x[base + 4];
  short8 o;
  o[0] = f2bf(a[0]); o[1] = f2bf(a[1]); o[2] = f2bf(a[2]); o[3] = f2bf(a[3]);
  o[4] = f2bf(b[0]); o[5] = f2bf(b[1]); o[6] = f2bf(b[2]); o[7] = f2bf(b[3]);
  *(short8*)&xb[base] = o;
}

// ---------------- transpose all 4 weights W[K][N] f32 -> WT[N][K] bf16 ----------------
__global__ __launch_bounds__(256) void twb4_k(const float* __restrict__ W1l,
    const float* __restrict__ W1r, const float* __restrict__ W2l,
    const float* __restrict__ W2r, short* __restrict__ WT1,
    short* __restrict__ WT2) {
  __shared__ float tile[32][33];
  int z = blockIdx.z;
  const float* W; short* WT; int K, N;
  if (z == 0)      { W = W1l; WT = WT1;             K = INC; N = D1;  }
  else if (z == 1) { W = W1r; WT = WT1 + D1 * INC;  K = INC; N = D1;  }
  else if (z == 2) { W = W2l; WT = WT2;             K = D1;  N = OUTC; }
  else             { W = W2r; WT = WT2 + OUTC * D1; K = D1;  N = OUTC; }
  if ((int)blockIdx.x >= N / 32 || (int)blockIdx.y >= K / 32) return;
  int tx = threadIdx.x & 31, ty = threadIdx.x >> 5;
  int n0 = blockIdx.x * 32, k0 = blockIdx.y * 32;
#pragma unroll
  for (int i = 0; i < 4; ++i)
    tile[ty + i * 8][tx] = W[(size_t)(k0 + ty + i * 8) * N + n0 + tx];
  __syncthreads();
#pragma unroll
  for (int i = 0; i < 4; ++i) {
    int n = ty + i * 8;
    WT[(size_t)(n0 + n) * K + k0 + tx] = f2bf(tile[tx][n]);
  }
}

// ---------------- bf16 MFMA GEMM: C[M,Nc] = A[M,K] @ BT[Nc,K]^T, bf16 out ----------------
// 128x128 tile, BK=64, 4 waves (2x2), 4x4 16x16 frags per wave.
#define LDT 72
__global__ __launch_bounds__(256) void gemm_bf16_k(const short* __restrict__ A,
    const short* __restrict__ BT, short* __restrict__ C, int M, int K, int Nc) {
  __shared__ short As[128 * LDT];
  __shared__ short Bs[128 * LDT];
  const int tid = threadIdx.x;
  const int lane = tid & 63, wave = tid >> 6;
  const int wr = wave >> 1, wc = wave & 1;
  const int l15 = lane & 15, l4 = lane >> 4;
  const int bm = blockIdx.y * 128, bn = blockIdx.x * 128;

  f32x4 zero4 = {0.f, 0.f, 0.f, 0.f};
  f32x4 acc[4][4];
#pragma unroll
  for (int m = 0; m < 4; ++m)
#pragma unroll
    for (int n = 0; n < 4; ++n) acc[m][n] = zero4;

  for (int k0 = 0; k0 < K; k0 += 64) {
#pragma unroll
    for (int i = 0; i < 4; ++i) {
      int q = tid + 256 * i;
      int row = q >> 3, kc = q & 7;
      short8 va = {0, 0, 0, 0, 0, 0, 0, 0};
      int gr = bm + row;
      if (gr < M) va = *(const short8*)&A[(size_t)gr * K + k0 + kc * 8];
      *(short8*)&As[row * LDT + kc * 8] = va;
      short8 vb = *(const short8*)&BT[(size_t)(bn + row) * K + k0 + kc * 8];
      *(short8*)&Bs[row * LDT + kc * 8] = vb;
    }
    __syncthreads();
    short8 af[4][2], bf[4][2];
#pragma unroll
    for (int m = 0; m < 4; ++m)
#pragma unroll
      for (int kk = 0; kk < 2; ++kk)
        af[m][kk] = *(const short8*)&As[(wr * 64 + m * 16 + l15) * LDT + kk * 32 + l4 * 8];
#pragma unroll
    for (int n = 0; n < 4; ++n)
#pragma unroll
      for (int kk = 0; kk < 2; ++kk)
        bf[n][kk] = *(const short8*)&Bs[(wc * 64 + n * 16 + l15) * LDT + kk * 32 + l4 * 8];
#pragma unroll
    for (int kk = 0; kk < 2; ++kk)
#pragma unroll
      for (int m = 0; m < 4; ++m)
#pragma unroll
        for (int n = 0; n < 4; ++n)
          acc[m][n] = __builtin_amdgcn_mfma_f32_16x16x32_bf16(
              af[m][kk], bf[n][kk], acc[m][n], 0, 0, 0);
    __syncthreads();
  }
  // C/D layout (m89-verified): col = lane&15, row = (lane>>4)*4 + reg
#pragma unroll
  for (int m = 0; m < 4; ++m) {
    int row0 = bm + wr * 64 + m * 16 + l4 * 4;
#pragma unroll
    for (int r = 0; r < 4; ++r) {
      int row = row0 + r;
      if (row < M) {
#pragma unroll
        for (int n = 0; n < 4; ++n)
          C[(size_t)row * Nc + bn + wc * 64 + n * 16 + l15] = f2bf(acc[m][n][r]);
      }
    }
  }
}

// ---------------- CSR build ----------------
__global__ __launch_bounds__(256) void zero_i_k(int* __restrict__ p, int n) {
  int stride = gridDim.x * 256;
  for (int i = blockIdx.x * 256 + threadIdx.x; i < n; i += stride) p[i] = 0;
}

__global__ __launch_bounds__(256) void hist_k(const int* __restrict__ dsts,
                                              int* __restrict__ deg) {
  int e = blockIdx.x * 256 + threadIdx.x;
  if (e < NEDGES) atomicAdd(&deg[dsts[e]], 1);
}

__global__ __launch_bounds__(256) void bsum_k(const int* __restrict__ deg,
                                              int* __restrict__ bsum) {
  __shared__ int red[256];
  int t = threadIdx.x, i = blockIdx.x * 256 + t;
  red[t] = (i < NNODES) ? deg[i] : 0;
  __syncthreads();
#pragma unroll
  for (int off = 128; off > 0; off >>= 1) {
    if (t < off) red[t] += red[t + off];
    __syncthreads();
  }
  if (t == 0) bsum[blockIdx.x] = red[0];
}

__global__ __launch_bounds__(64) void bscan_k(const int* __restrict__ bsum,
                                              int* __restrict__ bscan) {
  if (threadIdx.x == 0) {
    int run = 0;
    for (int j = 0; j < NB; ++j) { bscan[j] = run; run += bsum[j]; }
  }
}

__global__ __launch_bounds__(256) void rowptr_k(const int* __restrict__ deg,
    const int* __restrict__ bscan, int* __restrict__ rowptr,
    int* __restrict__ cursor) {
  __shared__ int s[256];
  int t = threadIdx.x, b = blockIdx.x, i = b * 256 + t;
  int v = (i < NNODES) ? deg[i] : 0;
  s[t] = v;
  __syncthreads();
#pragma unroll
  for (int off = 1; off < 256; off <<= 1) {
    int y = (t >= off) ? s[t - off] : 0;
    __syncthreads();
    s[t] += y;
    __syncthreads();
  }
  if (i < NNODES) {
    int ex = bscan[b] + s[t] - v;
    rowptr[i] = ex;
    cursor[i] = ex;
  }
  if (b == 0 && t == 0) rowptr[NNODES] = NEDGES;
}

__global__ __launch_bounds__(256) void scatter_k(const int* __restrict__ srcs,
    const int* __restrict__ dsts, int* __restrict__ cursor,
    int* __restrict__ col) {
  int e = blockIdx.x * 256 + threadIdx.x;
  if (e < NEDGES) {
    int pos = atomicAdd(&cursor[dsts[e]], 1);
    col[pos] = srcs[e];
  }
}

// ---------------- fused layer-1 ----------------
// X1b[d] row = [xl(512) | xr(512)] bf16. lane owns channels lane*8..+7, head = lane>>4.
// leaky(g) = 0.6g + 0.4|g|; |g| folds into fma abs-modifier.
__global__ __launch_bounds__(256) void fused1_k(const int* __restrict__ rowptr,
    const int* __restrict__ col, const short* __restrict__ X1b,
    const float* __restrict__ a1, const float* __restrict__ b1,
    short* __restrict__ Hb) {
  int d = blockIdx.x * 4 + (threadIdx.x >> 6);
  if (d >= NNODES) return;
  int lane = threadIdx.x & 63;
  int c0 = lane * 8;
  const size_t drow = (size_t)d * 1024;
  float av[8], xr[8], acc[8];
  short8 vself = *(const short8*)&X1b[drow + c0];
  short8 vxr   = *(const short8*)&X1b[drow + 512 + c0];
#pragma unroll
  for (int t = 0; t < 8; ++t) {
    av[t] = a1[c0 + t];
    xr[t] = bf2f(vxr[t]);
    acc[t] = 0.f;
  }
  float den = 0.f;
  {  // self loop
    float xl[8], pl = 0.f, pa = 0.f;
#pragma unroll
    for (int t = 0; t < 8; ++t) {
      xl[t] = bf2f(vself[t]);
      float g = xl[t] + xr[t];
      pl = fmaf(av[t], g, pl);
      pa = fmaf(av[t], fabsf(g), pa);
    }
    float sc = fmaf(0.6f, pl, 0.4f * pa);
    sc += __shfl_xor(sc, 1); sc += __shfl_xor(sc, 2);
    sc += __shfl_xor(sc, 4); sc += __shfl_xor(sc, 8);
    float p = __expf(sc);
    den += p;
#pragma unroll
    for (int t = 0; t < 8; ++t) acc[t] = fmaf(p, xl[t], acc[t]);
  }
  int beg = rowptr[d], end = rowptr[d + 1];
  int i = beg;
  for (; i + 1 < end; i += 2) {
    int s0 = col[i], s1 = col[i + 1];
    short8 v0 = *(const short8*)&X1b[(size_t)s0 * 1024 + c0];
    short8 v1 = *(const short8*)&X1b[(size_t)s1 * 1024 + c0];
    float xl0[8], xl1[8];
    float pl0 = 0.f, pa0 = 0.f, pl1 = 0.f, pa1 = 0.f;
#pragma unroll
    for (int t = 0; t < 8; ++t) {
      xl0[t] = bf2f(v0[t]);
      float g0 = xl0[t] + xr[t];
      pl0 = fmaf(av[t], g0, pl0);
      pa0 = fmaf(av[t], fabsf(g0), pa0);
      xl1[t] = bf2f(v1[t]);
      float g1 = xl1[t] + xr[t];
      pl1 = fmaf(av[t], g1, pl1);
      pa1 = fmaf(av[t], fabsf(g1), pa1);
    }
    float sc0 = fmaf(0.6f, pl0, 0.4f * pa0);
    float sc1 = fmaf(0.6f, pl1, 0.4f * pa1);
    sc0 += __shfl_xor(sc0, 1); sc1 += __shfl_xor(sc1, 1);
    sc0 += __shfl_xor(sc0, 2); sc1 += __shfl_xor(sc1, 2);
    sc0 += __shfl_xor(sc0, 4); sc1 += __shfl_xor(sc1, 4);
    sc0 += __shfl_xor(sc0, 8); sc1 += __shfl_xor(sc1, 8);
    float e0 = __expf(sc0), e1 = __expf(sc1);
    den += e0 + e1;
#pragma unroll
    for (int t = 0; t < 8; ++t) {
      acc[t] = fmaf(e0, xl0[t], acc[t]);
      acc[t] = fmaf(e1, xl1[t], acc[t]);
    }
  }
  if (i < end) {
    int s = col[i];
    short8 v = *(const short8*)&X1b[(size_t)s * 1024 + c0];
    float xl[8], pl = 0.f, pa = 0.f;
#pragma unroll
    for (int t = 0; t < 8; ++t) {
      xl[t] = bf2f(v[t]);
      float g = xl[t] + xr[t];
      pl = fmaf(av[t], g, pl);
      pa = fmaf(av[t], fabsf(g), pa);
    }
    float sc = fmaf(0.6f, pl, 0.4f * pa);
    sc += __shfl_xor(sc, 1); sc += __shfl_xor(sc, 2);
    sc += __shfl_xor(sc, 4); sc += __shfl_xor(sc, 8);
    float p = __expf(sc);
    den += p;
#pragma unroll
    for (int t = 0; t < 8; ++t) acc[t] = fmaf(p, xl[t], acc[t]);
  }
  float inv = 1.0f / den;   // one divide per node (vs 8)
  short8 o;
#pragma unroll
  for (int t = 0; t < 8; ++t) {
    float hv = fmaf(acc[t], inv, b1[c0 + t]);
    o[t] = f2bf(fmaxf(hv, 0.f));
  }
  *(short8*)&Hb[(size_t)d * D1 + c0] = o;
}

// ---------------- fused layer-2 ----------------
// X2b[d] row = [xl(256) | xr(256)] bf16. lane owns channels lane*4..+3, 1 head.
__global__ __launch_bounds__(256) void fused2_k(const int* __restrict__ rowptr,
    const int* __restrict__ col, const short* __restrict__ X2b,
    const float* __restrict__ a2, const float* __restrict__ b2,
    float* __restrict__ out) {
  int d = blockIdx.x * 4 + (threadIdx.x >> 6);
  if (d >= NNODES) return;
  int lane = threadIdx.x & 63;
  int c0 = lane * 4;
  const size_t drow = (size_t)d * 512;
  float av[4], xr[4], acc[4];
  bf16x4 vself = *(const bf16x4*)&X2b[drow + c0];
  bf16x4 vxr   = *(const bf16x4*)&X2b[drow + 256 + c0];
#pragma unroll
  for (int t = 0; t < 4; ++t) {
    av[t] = a2[c0 + t];
    xr[t] = bf2f(vxr[t]);
    acc[t] = 0.f;
  }
  float den = 0.f;
  {  // self loop
    float xl[4], pl = 0.f, pa = 0.f;
#pragma unroll
    for (int t = 0; t < 4; ++t) {
      xl[t] = bf2f(vself[t]);
      float g = xl[t] + xr[t];
      pl = fmaf(av[t], g, pl);
      pa = fmaf(av[t], fabsf(g), pa);
    }
    float sc = fmaf(0.6f, pl, 0.4f * pa);
#pragma unroll
    for (int off = 1; off < 64; off <<= 1) sc += __shfl_xor(sc, off);
    float p = __expf(sc);
    den += p;
#pragma unroll
    for (int t = 0; t < 4; ++t) acc[t] = fmaf(p, xl[t], acc[t]);
  }
  int beg = rowptr[d], end = rowptr[d + 1];
  int i = beg;
  for (; i + 1 < end; i += 2) {
    int s0 = col[i], s1 = col[i + 1];
    bf16x4 v0 = *(const bf16x4*)&X2b[(size_t)s0 * 512 + c0];
    bf16x4 v1 = *(const bf16x4*)&X2b[(size_t)s1 * 512 + c0];
    float xl0[4], xl1[4];
    float pl0 = 0.f, pa0 = 0.f, pl1 = 0.f, pa1 = 0.f;
#pragma unroll
    for (int t = 0; t < 4; ++t) {
      xl0[t] = bf2f(v0[t]);
      float g0 = xl0[t] + xr[t];
      pl0 = fmaf(av[t], g0, pl0);
      pa0 = fmaf(av[t], fabsf(g0), pa0);
      xl1[t] = bf2f(v1[t]);
      float g1 = xl1[t] + xr[t];
      pl1 = fmaf(av[t], g1, pl1);
      pa1 = fmaf(av[t], fabsf(g1), pa1);
    }
    float sc0 = fmaf(0.6f, pl0, 0.4f * pa0);
    float sc1 = fmaf(0.6f, pl1, 0.4f * pa1);
#pragma unroll
    for (int off = 1; off < 64; off <<= 1) {
      sc0 += __shfl_xor(sc0, off);
      sc1 += __shfl_xor(sc1, off);
    }
    float e0 = __expf(sc0), e1 = __expf(sc1);
    den += e0 + e1;
#pragma unroll
    for (int t = 0; t < 4; ++t) {
      acc[t] = fmaf(e0, xl0[t], acc[t]);
      acc[t] = fmaf(e1, xl1[t], acc[t]);
    }
  }
  if (i < end) {
    int s = col[i];
    bf16x4 v = *(const bf16x4*)&X2b[(size_t)s * 512 + c0];
    float xl[4], pl = 0.f, pa = 0.f;
#pragma unroll
    for (int t = 0; t < 4; ++t) {
      xl[t] = bf2f(v[t]);
      float g = xl[t] + xr[t];
      pl = fmaf(av[t], g, pl);
      pa = fmaf(av[t], fabsf(g), pa);
    }
    float sc = fmaf(0.6f, pl, 0.4f * pa);
#pragma unroll
    for (int off = 1; off < 64; off <<= 1) sc += __shfl_xor(sc, off);
    float p = __expf(sc);
    den += p;
#pragma unroll
    for (int t = 0; t < 4; ++t) acc[t] = fmaf(p, xl[t], acc[t]);
  }
  float inv = 1.0f / den;
  f32x4 o;
#pragma unroll
  for (int t = 0; t < 4; ++t) o[t] = fmaf(acc[t], inv, b2[c0 + t]);
  *(f32x4*)&out[(size_t)d * OUTC + c0] = o;
}

extern "C" void kernel_launch(void* const* d_in, const int* in_sizes, int n_in,
                              void* d_out, int out_size, void* d_ws, size_t ws_size,
                              hipStream_t stream) {
  const float* x   = (const float*)d_in[0];
  const int*   ei  = (const int*)d_in[1];
  const float* W1l = (const float*)d_in[2];
  const float* W1r = (const float*)d_in[3];
  const float* a1  = (const float*)d_in[4];
  const float* b1  = (const float*)d_in[5];
  const float* W2l = (const float*)d_in[6];
  const float* W2r = (const float*)d_in[7];
  const float* a2  = (const float*)d_in[8];
  const float* b2  = (const float*)d_in[9];
  float* out = (float*)d_out;
  char* ws = (char*)d_ws;

  // ---- workspace layout (~106 MB high-water) ----
  short* X1b   = (short*)(ws + 0);            // 50000x1024 bf16 = 102.4 MB
  short* X2b   = (short*)(ws + 0);            // 50000x512 bf16 = 51.2 MB (reuse after fused1)
  short* WT1   = (short*)(ws + 102400000);    // 1024x256 bf16 = 524288 B
  short* WT2   = (short*)(ws + 102924288);    // 512x512 bf16 = 524288 B
  int* rowptr  = (int*)(ws + 103448576);      // 200004 B
  int* cursor  = (int*)(ws + 103648640);      // 200000 B
  int* colv    = (int*)(ws + 103848640);      // 1.6 MB
  int* deg     = (int*)(ws + 105448640);      // 200000 B
  int* bsum    = (int*)(ws + 105648640);
  int* bscan   = (int*)(ws + 105649536);
  // d_out doubles as scratch: XB (25.6 MB) then Hb (51.2 MB = out_size)
  short* XB = (short*)d_out;
  short* Hb = (short*)d_out;

  const int* srcs = ei;
  const int* dsts = ei + NEDGES;

  dim3 blk(256);
  int eblk = (NEDGES + 255) / 256;
  int nblk4 = (NNODES + 3) / 4;

  // ---- CSR build (grouped by dst) ----
  zero_i_k<<<64, blk, 0, stream>>>(deg, NNODES);
  hist_k<<<eblk, blk, 0, stream>>>(dsts, deg);
  bsum_k<<<NB, blk, 0, stream>>>(deg, bsum);
  bscan_k<<<1, 64, 0, stream>>>(bsum, bscan);
  rowptr_k<<<NB, blk, 0, stream>>>(deg, bscan, rowptr, cursor);
  scatter_k<<<eblk, blk, 0, stream>>>(srcs, dsts, cursor, colv);

  // ---- bf16 prep: x and concatenated transposed weights (one launch) ----
  cvt_x_k<<<(NNODES * INC) / 2048, blk, 0, stream>>>(x, XB);
  twb4_k<<<dim3(16, 16, 4), blk, 0, stream>>>(W1l, W1r, W2l, W2r, WT1, WT2);

  // ---- layer 1: one merged GEMM -> X1b = [xl | xr] bf16 ----
  gemm_bf16_k<<<dim3(1024 / 128, (NNODES + 127) / 128), blk, 0, stream>>>(
      XB, WT1, X1b, NNODES, INC, 1024);

  // ---- layer 1 fused attention -> Hb = bf16(relu(.+b1)) in d_out ----
  fused1_k<<<nblk4, blk, 0, stream>>>(rowptr, colv, X1b, a1, b1, Hb);

  // ---- layer 2: one merged GEMM -> X2b = [xl | xr] bf16 ----
  gemm_bf16_k<<<dim3(512 / 128, (NNODES + 127) / 128), blk, 0, stream>>>(
      Hb, WT2, X2b, NNODES, D1, 512);

  // ---- layer 2 fused attention -> out (+b2) ----
  fused2_k<<<nblk4, blk, 0, stream>>>(rowptr, colv, X2b, a2, b2, out);
}